// Round 14
// baseline (603.242 us; speedup 1.0000x reference)
//
#include <hip/hip_runtime.h>

#define NN 100000
#define NE 1600000
#define SF 16
#define DF 32
#define EFT 8
#define HF 64

typedef __attribute__((ext_vector_type(8))) _Float16 half8;
typedef __attribute__((ext_vector_type(4))) _Float16 half4v;
typedef __attribute__((ext_vector_type(2))) _Float16 half2v;
typedef __attribute__((ext_vector_type(2))) __fp16 fp16x2;
typedef __attribute__((ext_vector_type(8))) short short8;
typedef __attribute__((ext_vector_type(4))) float floatx4;
typedef __attribute__((ext_vector_type(2))) float floatx2;

__device__ inline half2v pkrtz2(float a, float b) {
  fp16x2 t = __builtin_amdgcn_cvt_pkrtz(a, b);
  return __builtin_bit_cast(half2v, t);
}

// pack 4 f32 -> 4 fp8(e4m3) in one dword
__device__ inline unsigned int pk_fp8x4(float a, float b, float c, float d) {
  int v = __builtin_amdgcn_cvt_pk_fp8_f32(a, b, 0, false);
  v = __builtin_amdgcn_cvt_pk_fp8_f32(c, d, v, true);
  return (unsigned int)v;
}
// unpack 8 fp8 -> half8
__device__ inline half8 oct2h8(uint2 w) {
  floatx2 a = __builtin_amdgcn_cvt_pk_f32_fp8((int)w.x, false);
  floatx2 b = __builtin_amdgcn_cvt_pk_f32_fp8((int)w.x, true);
  floatx2 c = __builtin_amdgcn_cvt_pk_f32_fp8((int)w.y, false);
  floatx2 d = __builtin_amdgcn_cvt_pk_f32_fp8((int)w.y, true);
  half2v p0 = pkrtz2(a[0], a[1]);
  half2v p1 = pkrtz2(b[0], b[1]);
  half2v p2 = pkrtz2(c[0], c[1]);
  half2v p3 = pkrtz2(d[0], d[1]);
  half8 r;
  r[0]=p0[0]; r[1]=p0[1]; r[2]=p1[0]; r[3]=p1[1];
  r[4]=p2[0]; r[5]=p2[1]; r[6]=p3[0]; r[7]=p3[1];
  return r;
}

// ---------------- CSR build ----------------
__global__ __launch_bounds__(256) void hist_kernel(const int* __restrict__ ei,
                                                   int* __restrict__ deg) {
  int e = blockIdx.x * 256 + threadIdx.x;
  if (e < NE) atomicAdd(&deg[ei[NE + e]], 1);
}

__global__ __launch_bounds__(256) void scan1_kernel(const int* __restrict__ deg,
                                                    int* __restrict__ cur,
                                                    int* __restrict__ bsums) {
  __shared__ int ts[256];
  int tid = threadIdx.x;
  int base = blockIdx.x * 1024 + tid * 4;
  int v[4];
#pragma unroll
  for (int q = 0; q < 4; ++q) v[q] = (base + q < NN) ? deg[base + q] : 0;
  int s = v[0] + v[1] + v[2] + v[3];
  ts[tid] = s;
  __syncthreads();
  for (int off = 1; off < 256; off <<= 1) {
    int t = (tid >= off) ? ts[tid - off] : 0;
    __syncthreads();
    ts[tid] += t;
    __syncthreads();
  }
  int excl = ts[tid] - s;
  if (tid == 255) bsums[blockIdx.x] = ts[255];
  int run = excl;
#pragma unroll
  for (int q = 0; q < 4; ++q) {
    if (base + q < NN) cur[base + q] = run;
    run += v[q];
  }
}

__global__ __launch_bounds__(256) void scan3_kernel(int* __restrict__ cur,
                                                    const int* __restrict__ bsums) {
  int i = blockIdx.x * 256 + threadIdx.x;
  int g = blockIdx.x >> 2;
  int pref = 0;
  for (int q = 0; q < g; ++q) pref += bsums[q];
  if (i < NN) cur[i] += pref;
}

// ---- setup: zero scattered+deg; pack WpreT, W2 frags, W1e^T frags (f16) ----
__global__ __launch_bounds__(256) void setup_kernel(
    const float* __restrict__ W1, const float* __restrict__ W2,
    _Float16* __restrict__ WpreT, _Float16* __restrict__ w2pk,
    _Float16* __restrict__ w1epk,
    float4* __restrict__ scattered4, int* __restrict__ deg) {
  int gid = blockIdx.x * 256 + threadIdx.x;
  if (gid < 800000) {
    float4 z = {0.f, 0.f, 0.f, 0.f};
    scattered4[gid] = z;
  }
  if (gid < NN) deg[gid] = 0;
  if (gid < 128 * 64) {
    int col = gid >> 6, k = gid & 63;
    int j = col & 63;
    bool bh = col >= 64;
    float v = 0.f;
    if (k < 16) v = W1[((bh ? 16 : 0) + k) * HF + j];
    else if (k < 48) v = W1[((bh ? 64 : 32) + (k - 16)) * HF + j];
    WpreT[gid] = (_Float16)v;
  }
  if (gid < 2048) {
    // W2 B-frags: lane holds col = nt*16+lcol, k = kt*32 + kgrp*8 + q
    int lane = gid >> 5, idx = gid & 31;
    int kt = idx >> 4, nt = (idx >> 3) & 1, q = idx & 7;
    int kgrp = (lane >> 4) & 3, lcol = lane & 15;
    w2pk[gid] = (_Float16)W2[(kt * 32 + kgrp * 8 + q) * DF + nt * 16 + lcol];
  } else if (gid < 4096) {
    // W1e^T A-frags: lane<16 holds row j=lane (within jblk), k=t (k>=8 -> 0)
    int id = gid - 2048;  // lane*32 + jblk*8 + t
    int lane = id >> 5, idx = id & 31;
    int jblk = idx >> 3, t = idx & 7;
    float v = (lane < 16) ? W1[(96 + t) * HF + jblk * 16 + lane] : 0.f;
    w1epk[id] = (_Float16)v;
  }
}

// ---- fill: packed 24B sorted records {int r, int c, half ea[8]} ----
__global__ __launch_bounds__(256) void fill_kernel(
    const int* __restrict__ ei, const float* __restrict__ ea,
    int* __restrict__ cur, char* __restrict__ recs) {
  int e = blockIdx.x * 256 + threadIdx.x;
  int r = ei[e];
  int c = ei[NE + e];
  int pos = atomicAdd(&cur[c], 1);
  const float4* p = (const float4*)(ea + (size_t)e * EFT);
  float4 v0 = p[0], v1 = p[1];
  union { _Float16 h[2]; int i; } p01, p23, p45, p67;
  p01.h[0] = (_Float16)v0.x; p01.h[1] = (_Float16)v0.y;
  p23.h[0] = (_Float16)v0.z; p23.h[1] = (_Float16)v0.w;
  p45.h[0] = (_Float16)v1.x; p45.h[1] = (_Float16)v1.y;
  p67.h[0] = (_Float16)v1.z; p67.h[1] = (_Float16)v1.w;
  int2* rp = (int2*)(recs + (size_t)pos * 24);
  int2 a = {r, c};
  int2 b = {p01.i, p23.i};
  int2 d = {p45.i, p67.i};
  rp[0] = a; rp[1] = b; rp[2] = d;
}

// ---------------- init: out = x_t @ F[0]; also outb(f16), sums ----------------
__global__ __launch_bounds__(256) void init_kernel(
    const float* __restrict__ x_t, const float* __restrict__ F0,
    float* __restrict__ out, _Float16* __restrict__ outb,
    float* __restrict__ sums) {
  int n = blockIdx.x * 256 + threadIdx.x;
  if (n >= NN) return;
  float x[DF];
  const float4* xr = reinterpret_cast<const float4*>(x_t + (size_t)n * DF);
#pragma unroll
  for (int q = 0; q < 8; ++q) {
    float4 v = xr[q];
    x[4*q+0]=v.x; x[4*q+1]=v.y; x[4*q+2]=v.z; x[4*q+3]=v.w;
  }
  float4* orow = reinterpret_cast<float4*>(out + (size_t)n * DF);
  _Float16* ob = outb + (size_t)n * DF;
  float s = 0.f;
#pragma unroll
  for (int q = 0; q < 8; ++q) {
    float4 acc = {0.f, 0.f, 0.f, 0.f};
#pragma unroll
    for (int i = 0; i < DF; ++i) {
      float xi = x[i];
      acc.x = fmaf(xi, F0[i*DF + 4*q+0], acc.x);
      acc.y = fmaf(xi, F0[i*DF + 4*q+1], acc.y);
      acc.z = fmaf(xi, F0[i*DF + 4*q+2], acc.z);
      acc.w = fmaf(xi, F0[i*DF + 4*q+3], acc.w);
    }
    orow[q] = acc;
    s += acc.x + acc.y + acc.z + acc.w;
    half4v pk = {(_Float16)acc.x, (_Float16)acc.y, (_Float16)acc.z, (_Float16)acc.w};
    *(half4v*)(ob + 4*q) = pk;
  }
  sums[n] = s;
}

// ------- pre (f16 MFMA): ABh[n][128] = [xs|out|0] @ Wpre -------
__global__ __launch_bounds__(256, 4) void pre_kernel(
    const float* __restrict__ x_s, const _Float16* __restrict__ outb,
    const _Float16* __restrict__ WpreT, _Float16* __restrict__ ABh) {
  __shared__ _Float16 wlds[128][72];
  __shared__ _Float16 st[64][136];  // C-frag transpose staging
  int tid = threadIdx.x;
  for (int t = tid; t < 1024; t += 256) {
    int colr = t >> 3, kc = t & 7;
    *(half8*)(&wlds[colr][kc * 8]) = *(const half8*)(WpreT + colr * 64 + kc * 8);
  }
  __syncthreads();

  int lcol = tid & 15, kgrp = (tid >> 4) & 3, wid = tid >> 6;
  int nodebase = blockIdx.x * 64 + wid * 16;
  int nodeA = nodebase + lcol;

  half8 a0 = {}, a1 = {};
  if (nodeA < NN) {
    const _Float16* obp = outb + (size_t)nodeA * DF;
    if (kgrp < 2) {
      const float4* p = (const float4*)(x_s + (size_t)nodeA * SF);
      float4 v0 = p[kgrp * 2], v1 = p[kgrp * 2 + 1];
      a0[0]=(_Float16)v0.x; a0[1]=(_Float16)v0.y;
      a0[2]=(_Float16)v0.z; a0[3]=(_Float16)v0.w;
      a0[4]=(_Float16)v1.x; a0[5]=(_Float16)v1.y;
      a0[6]=(_Float16)v1.z; a0[7]=(_Float16)v1.w;
      a1 = *(const half8*)(obp + 16 + kgrp * 8);
    } else if (kgrp == 2) {
      a0 = *(const half8*)(obp + 0);
    } else {
      a0 = *(const half8*)(obp + 8);
    }
  }

  floatx4 acc[8];
#pragma unroll
  for (int nt = 0; nt < 8; ++nt) {
    half8 b0 = *(const half8*)(&wlds[nt * 16 + lcol][kgrp * 8]);
    half8 b1v = *(const half8*)(&wlds[nt * 16 + lcol][32 + kgrp * 8]);
    floatx4 c = {0.f, 0.f, 0.f, 0.f};
    c = __builtin_amdgcn_mfma_f32_16x16x32_f16(a0, b0, c, 0, 0, 0);
    c = __builtin_amdgcn_mfma_f32_16x16x32_f16(a1, b1v, c, 0, 0, 0);
    acc[nt] = c;
  }

  // stage C-frags in LDS (wave-local rows), then coalesced 64B global writes
#pragma unroll
  for (int nt = 0; nt < 8; ++nt) {
#pragma unroll
    for (int rr = 0; rr < 4; ++rr)
      st[wid * 16 + kgrp * 4 + rr][nt * 16 + lcol] = (_Float16)acc[nt][rr];
  }
  // wave w reads nodes 16w..16w+15 (its own writes; same-wave LDS is ordered)
  int nl = tid >> 2, q = tid & 3;
  int node = blockIdx.x * 64 + nl;
  if (node < NN) {
    _Float16* dst = ABh + (size_t)node * 128 + q * 32;
#pragma unroll
    for (int s = 0; s < 4; ++s)
      *(half8*)(dst + s * 8) = *(const half8*)(&st[nl][q * 32 + s * 8]);
  }
}

// ---------------- edge MLP (f16 MFMA, fp8 h-tile) + owner epilogue ----------------
__global__ __launch_bounds__(256, 8) void edge_kernel(
    const _Float16* __restrict__ ABh, const _Float16* __restrict__ outb,
    const float* __restrict__ sums, const char* __restrict__ recs,
    const float* __restrict__ b1, const float* __restrict__ b2,
    const _Float16* __restrict__ w2pk, const _Float16* __restrict__ w1epk,
    float* __restrict__ scattered) {
  // One 72B-stride row per edge, two views with IDENTICAL row ranges:
  //   fp8 h view: bytes [r*72, r*72+64)   (phases 0-2)
  //   f16 sh view: halves [r*36, r*36+32) (phases 3-4)
  // -> all of phases 0-3 are wave-local (rows 64w..64w+63); no mid barrier.
  __shared__ unsigned short lds[256 * 36];  // 18432 B
  __shared__ int scol[256];
  __shared__ unsigned char l0[256], lenm1[256];
  __shared__ int wbase[4];
  __shared__ int cnt;

  unsigned char* hb = (unsigned char*)lds;
  _Float16* shh = (_Float16*)lds;

  int tid = threadIdx.x;
  int bbase = blockIdx.x * 256;
  int i = bbase + tid;  // NE % 256 == 0: always valid
  if (tid == 0) cnt = 0;
  int lcol = tid & 15, kgrp = (tid >> 4) & 3, wid = tid >> 6;
  int lane = tid & 63;

  // load packed record {r, c, ea[8] f16}
  const int2* rp = (const int2*)(recs + (size_t)i * 24);
  int2 ra = rp[0], rb = rp[1], rd = rp[2];
  int r = ra.x;
  int c = ra.y;
  int4 eai = {rb.x, rb.y, rd.x, rd.y};
  scol[tid] = c;
  float s_r = sums[r], s_c = sums[c];

  // EARLY-ISSUE: stage A[r] and B[c] halves (128B each) into registers so
  // the HBM/L3 latency hides under phase-0's shuffles + MFMAs.
  half8 Ar[8], Bc[8];
  {
    const half8* arp = (const half8*)(ABh + (size_t)r * 128);
    const half8* bcp = (const half8*)(ABh + (size_t)c * 128 + 64);
#pragma unroll
    for (int q = 0; q < 8; ++q) { Ar[q] = arp[q]; Bc[q] = bcp[q]; }
  }

  float b2c0 = b2[lcol], b2c1 = b2[16 + lcol];

  // ---- phase 0: eaw^T = W1e^T @ ea via swapped MFMA -> fp8 dword writes ----
  const _Float16* wep = w1epk + (size_t)lane * 32;
  half8 wA0 = *(const half8*)(wep);
  half8 wA1 = *(const half8*)(wep + 8);
  half8 wA2 = *(const half8*)(wep + 16);
  half8 wA3 = *(const half8*)(wep + 24);
  const float4* b1f4 = (const float4*)b1;
  float4 b1q0 = b1f4[0 + kgrp];
  float4 b1q1 = b1f4[4 + kgrp];
  float4 b1q2 = b1f4[8 + kgrp];
  float4 b1q3 = b1f4[12 + kgrp];
  bool lo16 = lane < 16;
#pragma unroll
  for (int g = 0; g < 4; ++g) {
    int src = g * 16 + lcol;
    int4 t;
    t.x = __shfl(eai.x, src, 64);
    t.y = __shfl(eai.y, src, 64);
    t.z = __shfl(eai.z, src, 64);
    t.w = __shfl(eai.w, src, 64);
    half8 zz = {};
    half8 bg = lo16 ? __builtin_bit_cast(half8, t) : zz;
    int erow = wid * 64 + g * 16 + lcol;
    unsigned char* hrow = hb + erow * 72 + kgrp * 4;
    {
      floatx4 cc = {b1q0.x, b1q0.y, b1q0.z, b1q0.w};
      cc = __builtin_amdgcn_mfma_f32_16x16x32_f16(wA0, bg, cc, 0, 0, 0);
      *(unsigned int*)(hrow + 0)  = pk_fp8x4(cc[0], cc[1], cc[2], cc[3]);
    }
    {
      floatx4 cc = {b1q1.x, b1q1.y, b1q1.z, b1q1.w};
      cc = __builtin_amdgcn_mfma_f32_16x16x32_f16(wA1, bg, cc, 0, 0, 0);
      *(unsigned int*)(hrow + 16) = pk_fp8x4(cc[0], cc[1], cc[2], cc[3]);
    }
    {
      floatx4 cc = {b1q2.x, b1q2.y, b1q2.z, b1q2.w};
      cc = __builtin_amdgcn_mfma_f32_16x16x32_f16(wA2, bg, cc, 0, 0, 0);
      *(unsigned int*)(hrow + 32) = pk_fp8x4(cc[0], cc[1], cc[2], cc[3]);
    }
    {
      floatx4 cc = {b1q3.x, b1q3.y, b1q3.z, b1q3.w};
      cc = __builtin_amdgcn_mfma_f32_16x16x32_f16(wA3, bg, cc, 0, 0, 0);
      *(unsigned int*)(hrow + 48) = pk_fp8x4(cc[0], cc[1], cc[2], cc[3]);
    }
  }

  // ---- phase 1: h = relu(A[r] + B[c] + eaw), fp8 RMW on own row ----
#pragma unroll
  for (int q = 0; q < 8; ++q) {
    unsigned char* p = hb + tid * 72 + q * 8;
    uint2 w = *(const uint2*)p;
    half8 wf = oct2h8(w);
    half8 s = Ar[q] + Bc[q] + wf;
    short8 sb = __builtin_bit_cast(short8, s);
    short8 m = sb >> 15;
    sb = sb & ~m;  // relu: zero negatives (and -0)
    half8 sr = __builtin_bit_cast(half8, sb);
    uint2 o;
    o.x = pk_fp8x4((float)sr[0], (float)sr[1], (float)sr[2], (float)sr[3]);
    o.y = pk_fp8x4((float)sr[4], (float)sr[5], (float)sr[6], (float)sr[7]);
    *(uint2*)p = o;
  }

  // ---- phase 2: layer-2 MFMA, 4 groups of 16 edges per wave ----
  const _Float16* wpp = w2pk + (size_t)lane * 32;
  half8 w2f00 = *(const half8*)(wpp);
  half8 w2f01 = *(const half8*)(wpp + 8);
  half8 w2f10 = *(const half8*)(wpp + 16);
  half8 w2f11 = *(const half8*)(wpp + 24);
  floatx4 acc[4][2];
#pragma unroll
  for (int g = 0; g < 4; ++g) {
    int erow = wid * 64 + g * 16 + lcol;
    const unsigned char* hr = hb + erow * 72;
    half8 a0 = oct2h8(*(const uint2*)(hr + kgrp * 8));
    half8 a1 = oct2h8(*(const uint2*)(hr + 32 + kgrp * 8));
    floatx4 c0 = {b2c0, b2c0, b2c0, b2c0};
    floatx4 c1 = {b2c1, b2c1, b2c1, b2c1};
    c0 = __builtin_amdgcn_mfma_f32_16x16x32_f16(a0, w2f00, c0, 0, 0, 0);
    c0 = __builtin_amdgcn_mfma_f32_16x16x32_f16(a1, w2f10, c0, 0, 0, 0);
    c1 = __builtin_amdgcn_mfma_f32_16x16x32_f16(a0, w2f01, c1, 0, 0, 0);
    c1 = __builtin_amdgcn_mfma_f32_16x16x32_f16(a1, w2f11, c1, 0, 0, 0);
    acc[g][0] = c0;
    acc[g][1] = c1;
  }

  // EARLY-ISSUE: outb rows for the epilogue.
  half8 Or[4], Oc[4];
  {
    const half8* orp = (const half8*)(outb + (size_t)r * DF);
    const half8* ocp = (const half8*)(outb + (size_t)c * DF);
#pragma unroll
    for (int q = 0; q < 4; ++q) { Or[q] = orp[q]; Oc[q] = ocp[q]; }
  }

  // ---- phase 3a: dump o (C-frags) to f16 sh view (same wave-local rows;
  //      acc data-dependency orders these after phase-2 LDS reads) ----
#pragma unroll
  for (int g = 0; g < 4; ++g) {
#pragma unroll
    for (int rr = 0; rr < 4; ++rr) {
      int e = wid * 64 + g * 16 + kgrp * 4 + rr;
      shh[e * 36 + lcol]      = (_Float16)acc[g][0][rr];
      shh[e * 36 + 16 + lcol] = (_Float16)acc[g][1][rr];
    }
  }

  // ---- phase 3b: owner-centric norm + mask + shift (wave-local) ----
  {
    float o2[32];
    float nsq = 0.f;
#pragma unroll
    for (int m = 0; m < 8; ++m) {
      uint2 w = *(const uint2*)(hb + tid * 72 + m * 8);
      half4v hv = __builtin_bit_cast(half4v, w);
#pragma unroll
      for (int jj = 0; jj < 4; ++jj) {
        float v = (float)hv[jj];
        o2[m * 4 + jj] = v;
        nsq = fmaf(v, v, nsq);
      }
    }
    float ms = (nsq > 0.f) ? rsqrtf(nsq) : 0.f;
    if (s_r == 0.f && s_c == 0.f) ms = 0.f;
#pragma unroll
    for (int m = 0; m < 8; ++m) {
      int q = m >> 1, base = (m & 1) * 4;
      float f0 = ((float)Oc[q][base+0] - (float)Or[q][base+0]) * o2[m*4+0] * ms;
      float f1 = ((float)Oc[q][base+1] - (float)Or[q][base+1]) * o2[m*4+1] * ms;
      float f2 = ((float)Oc[q][base+2] - (float)Or[q][base+2]) * o2[m*4+2] * ms;
      float f3 = ((float)Oc[q][base+3] - (float)Or[q][base+3]) * o2[m*4+3] * ms;
      half2v p0 = pkrtz2(f0, f1);
      half2v p1 = pkrtz2(f2, f3);
      uint2 o;
      o.x = __builtin_bit_cast(unsigned int, p0);
      o.y = __builtin_bit_cast(unsigned int, p1);
      *(uint2*)(hb + tid * 72 + m * 8) = o;
    }
  }
  __syncthreads();  // cross-wave: sh rows + scol + cnt now visible

  // ---- phase 4: segmented reduce over sorted-col runs ----
  int c_self = scol[tid];
  bool head = (tid == 0 || scol[tid - 1] != c_self);
  unsigned long long m = __ballot(head);
  if (lane == 0) wbase[wid] = atomicAdd(&cnt, (int)__popcll(m));
  __syncthreads();
  if (head) {
    int idx = wbase[wid] + (int)__popcll(m & ((1ull << lane) - 1ull));
    int t1 = tid + 1;
    while (t1 < 256 && scol[t1] == c_self) ++t1;
    l0[idx] = (unsigned char)tid;
    lenm1[idx] = (unsigned char)(t1 - tid - 1);
  }
  __syncthreads();
  int nr = cnt;
  for (int task = tid; task < nr * 32; task += 256) {
    int rid = task >> 5, j = task & 31;
    int t0 = l0[rid];
    int t1 = t0 + lenm1[rid] + 1;
    float s = 0.f;
    for (int t = t0; t < t1; ++t) s += (float)shh[t * 36 + j];
    unsafeAtomicAdd(&scattered[(size_t)scol[t0] * DF + j], s);
  }
}

// --- node update (in place): out += scattered @ Fk; outb/sums; clear sc ---
__global__ __launch_bounds__(256) void node_kernel(
    float* __restrict__ out, float* __restrict__ scattered,
    const float* __restrict__ Fk, _Float16* __restrict__ outb,
    float* __restrict__ sums) {
  int n = blockIdx.x * 256 + threadIdx.x;
  if (n >= NN) return;
  float s[DF];
  float4* sp = reinterpret_cast<float4*>(scattered + (size_t)n * DF);
#pragma unroll
  for (int q = 0; q < 8; ++q) {
    float4 v = sp[q];
    s[4*q+0]=v.x; s[4*q+1]=v.y; s[4*q+2]=v.z; s[4*q+3]=v.w;
  }
  float4* op = reinterpret_cast<float4*>(out + (size_t)n * DF);
  _Float16* ob = outb + (size_t)n * DF;
  float ssum = 0.f;
#pragma unroll
  for (int q = 0; q < 8; ++q) {
    float4 acc = op[q];
#pragma unroll
    for (int i = 0; i < DF; ++i) {
      float si = s[i];
      acc.x = fmaf(si, Fk[i*DF + 4*q+0], acc.x);
      acc.y = fmaf(si, Fk[i*DF + 4*q+1], acc.y);
      acc.z = fmaf(si, Fk[i*DF + 4*q+2], acc.z);
      acc.w = fmaf(si, Fk[i*DF + 4*q+3], acc.w);
    }
    op[q] = acc;
    ssum += acc.x + acc.y + acc.z + acc.w;
    half4v pk = {(_Float16)acc.x, (_Float16)acc.y, (_Float16)acc.z, (_Float16)acc.w};
    *(half4v*)(ob + 4*q) = pk;
  }
  sums[n] = ssum;
  float4 z = {0.f, 0.f, 0.f, 0.f};
#pragma unroll
  for (int q = 0; q < 8; ++q) sp[q] = z;
}

extern "C" void kernel_launch(void* const* d_in, const int* in_sizes, int n_in,
                              void* d_out, int out_size, void* d_ws, size_t ws_size,
                              hipStream_t stream) {
  const float* x_s = (const float*)d_in[0];
  const float* x_t = (const float*)d_in[1];
  const int*   ei  = (const int*)d_in[2];
  const float* ea  = (const float*)d_in[3];
  const float* W1  = (const float*)d_in[4];
  const float* b1  = (const float*)d_in[5];
  const float* W2  = (const float*)d_in[6];
  const float* b2  = (const float*)d_in[7];
  const float* F   = (const float*)d_in[8];

  float* out = (float*)d_out;
  char* ws = (char*)d_ws;
  float*     scattered = (float*)(ws);                  // 12.8 MB
  _Float16*  ABh       = (_Float16*)(ws + 12800000);    // 25.6 MB
  _Float16*  outb      = (_Float16*)(ws + 38400000);    // 6.4 MB
  float*     sums      = (float*)(ws + 44800000);       // 0.4 MB
  char*      recs      = (char*)(ws + 45200000);        // 38.4 MB (24B/edge)
  int*       deg       = (int*)(ws + 83600000);         // 0.4 MB
  int*       cur       = (int*)(ws + 84000000);         // 0.4 MB
  int*       bsums     = (int*)(ws + 84400000);         // 4 KB
  _Float16*  WpreT     = (_Float16*)(ws + 84410000);    // 16 KB
  _Float16*  w2pk      = (_Float16*)(ws + 84430000);    // 4 KB
  _Float16*  w1epk     = (_Float16*)(ws + 84440000);    // 4 KB

  dim3 blk(256);
  dim3 grid_e(NE / 256);          // 6250, exact
  dim3 grid_n((NN + 255) / 256);  // 391
  dim3 grid_p((NN + 63) / 64);    // 1563
  int nscan = (NN + 1023) / 1024; // 98

  setup_kernel<<<3125, blk, 0, stream>>>(W1, W2, WpreT, w2pk, w1epk,
                                         (float4*)scattered, deg);
  hist_kernel<<<grid_e, blk, 0, stream>>>(ei, deg);
  scan1_kernel<<<nscan, blk, 0, stream>>>(deg, cur, bsums);
  scan3_kernel<<<grid_n, blk, 0, stream>>>(cur, bsums);
  fill_kernel<<<grid_e, blk, 0, stream>>>(ei, ea, cur, recs);

  init_kernel<<<grid_n, blk, 0, stream>>>(x_t, F, out, outb, sums);

  for (int k = 0; k < 2; ++k) {
    pre_kernel<<<grid_p, blk, 0, stream>>>(x_s, outb, WpreT, ABh);
    edge_kernel<<<grid_e, blk, 0, stream>>>(ABh, outb, sums, recs, b1, b2,
                                            w2pk, w1epk, scattered);
    node_kernel<<<grid_n, blk, 0, stream>>>(out, scattered,
                                            F + (size_t)(k + 1) * DF * DF,
                                            outb, sums);
  }
}

// Round 15
// 469.035 us; speedup vs baseline: 1.2861x; 1.2861x over previous
//
#include <hip/hip_runtime.h>

#define NN 100000
#define NE 1600000
#define SF 16
#define DF 32
#define EFT 8
#define HF 64

typedef __attribute__((ext_vector_type(8))) _Float16 half8;
typedef __attribute__((ext_vector_type(4))) _Float16 half4v;
typedef __attribute__((ext_vector_type(2))) _Float16 half2v;
typedef __attribute__((ext_vector_type(2))) __fp16 fp16x2;
typedef __attribute__((ext_vector_type(8))) short short8;
typedef __attribute__((ext_vector_type(4))) float floatx4;
typedef __attribute__((ext_vector_type(2))) float floatx2;

__device__ inline half2v pkrtz2(float a, float b) {
  fp16x2 t = __builtin_amdgcn_cvt_pkrtz(a, b);
  return __builtin_bit_cast(half2v, t);
}

// pack 4 f32 -> 4 fp8(e4m3) in one dword
__device__ inline unsigned int pk_fp8x4(float a, float b, float c, float d) {
  int v = __builtin_amdgcn_cvt_pk_fp8_f32(a, b, 0, false);
  v = __builtin_amdgcn_cvt_pk_fp8_f32(c, d, v, true);
  return (unsigned int)v;
}
// unpack 8 fp8 -> half8
__device__ inline half8 oct2h8(uint2 w) {
  floatx2 a = __builtin_amdgcn_cvt_pk_f32_fp8((int)w.x, false);
  floatx2 b = __builtin_amdgcn_cvt_pk_f32_fp8((int)w.x, true);
  floatx2 c = __builtin_amdgcn_cvt_pk_f32_fp8((int)w.y, false);
  floatx2 d = __builtin_amdgcn_cvt_pk_f32_fp8((int)w.y, true);
  half2v p0 = pkrtz2(a[0], a[1]);
  half2v p1 = pkrtz2(b[0], b[1]);
  half2v p2 = pkrtz2(c[0], c[1]);
  half2v p3 = pkrtz2(d[0], d[1]);
  half8 r;
  r[0]=p0[0]; r[1]=p0[1]; r[2]=p1[0]; r[3]=p1[1];
  r[4]=p2[0]; r[5]=p2[1]; r[6]=p3[0]; r[7]=p3[1];
  return r;
}

// ---------------- CSR build ----------------
__global__ __launch_bounds__(256) void hist_kernel(const int* __restrict__ ei,
                                                   int* __restrict__ deg) {
  int e = blockIdx.x * 256 + threadIdx.x;
  if (e < NE) atomicAdd(&deg[ei[NE + e]], 1);
}

__global__ __launch_bounds__(256) void scan1_kernel(const int* __restrict__ deg,
                                                    int* __restrict__ cur,
                                                    int* __restrict__ bsums) {
  __shared__ int ts[256];
  int tid = threadIdx.x;
  int base = blockIdx.x * 1024 + tid * 4;
  int v[4];
#pragma unroll
  for (int q = 0; q < 4; ++q) v[q] = (base + q < NN) ? deg[base + q] : 0;
  int s = v[0] + v[1] + v[2] + v[3];
  ts[tid] = s;
  __syncthreads();
  for (int off = 1; off < 256; off <<= 1) {
    int t = (tid >= off) ? ts[tid - off] : 0;
    __syncthreads();
    ts[tid] += t;
    __syncthreads();
  }
  int excl = ts[tid] - s;
  if (tid == 255) bsums[blockIdx.x] = ts[255];
  int run = excl;
#pragma unroll
  for (int q = 0; q < 4; ++q) {
    if (base + q < NN) cur[base + q] = run;
    run += v[q];
  }
}

__global__ __launch_bounds__(256) void scan3_kernel(int* __restrict__ cur,
                                                    const int* __restrict__ bsums) {
  int i = blockIdx.x * 256 + threadIdx.x;
  int g = blockIdx.x >> 2;
  int pref = 0;
  for (int q = 0; q < g; ++q) pref += bsums[q];
  if (i < NN) cur[i] += pref;
}

// ---- setup: zero scattered+deg; pack WpreT, W2 frags, W1e^T frags (f16) ----
__global__ __launch_bounds__(256) void setup_kernel(
    const float* __restrict__ W1, const float* __restrict__ W2,
    _Float16* __restrict__ WpreT, _Float16* __restrict__ w2pk,
    _Float16* __restrict__ w1epk,
    float4* __restrict__ scattered4, int* __restrict__ deg) {
  int gid = blockIdx.x * 256 + threadIdx.x;
  if (gid < 800000) {
    float4 z = {0.f, 0.f, 0.f, 0.f};
    scattered4[gid] = z;
  }
  if (gid < NN) deg[gid] = 0;
  if (gid < 128 * 64) {
    int col = gid >> 6, k = gid & 63;
    int j = col & 63;
    bool bh = col >= 64;
    float v = 0.f;
    if (k < 16) v = W1[((bh ? 16 : 0) + k) * HF + j];
    else if (k < 48) v = W1[((bh ? 64 : 32) + (k - 16)) * HF + j];
    WpreT[gid] = (_Float16)v;
  }
  if (gid < 2048) {
    // W2 B-frags: lane holds col = nt*16+lcol, k = kt*32 + kgrp*8 + q
    int lane = gid >> 5, idx = gid & 31;
    int kt = idx >> 4, nt = (idx >> 3) & 1, q = idx & 7;
    int kgrp = (lane >> 4) & 3, lcol = lane & 15;
    w2pk[gid] = (_Float16)W2[(kt * 32 + kgrp * 8 + q) * DF + nt * 16 + lcol];
  } else if (gid < 4096) {
    // W1e^T A-frags: lane<16 holds row j=lane (within jblk), k=t (k>=8 -> 0)
    int id = gid - 2048;  // lane*32 + jblk*8 + t
    int lane = id >> 5, idx = id & 31;
    int jblk = idx >> 3, t = idx & 7;
    float v = (lane < 16) ? W1[(96 + t) * HF + jblk * 16 + lane] : 0.f;
    w1epk[id] = (_Float16)v;
  }
}

// ---- fill: packed 24B sorted records {int r, int c, half ea[8]} ----
__global__ __launch_bounds__(256) void fill_kernel(
    const int* __restrict__ ei, const float* __restrict__ ea,
    int* __restrict__ cur, char* __restrict__ recs) {
  int e = blockIdx.x * 256 + threadIdx.x;
  int r = ei[e];
  int c = ei[NE + e];
  int pos = atomicAdd(&cur[c], 1);
  const float4* p = (const float4*)(ea + (size_t)e * EFT);
  float4 v0 = p[0], v1 = p[1];
  union { _Float16 h[2]; int i; } p01, p23, p45, p67;
  p01.h[0] = (_Float16)v0.x; p01.h[1] = (_Float16)v0.y;
  p23.h[0] = (_Float16)v0.z; p23.h[1] = (_Float16)v0.w;
  p45.h[0] = (_Float16)v1.x; p45.h[1] = (_Float16)v1.y;
  p67.h[0] = (_Float16)v1.z; p67.h[1] = (_Float16)v1.w;
  int2* rp = (int2*)(recs + (size_t)pos * 24);
  int2 a = {r, c};
  int2 b = {p01.i, p23.i};
  int2 d = {p45.i, p67.i};
  rp[0] = a; rp[1] = b; rp[2] = d;
}

// ---------------- init: out = x_t @ F[0]; also outb(f16), sums ----------------
__global__ __launch_bounds__(256) void init_kernel(
    const float* __restrict__ x_t, const float* __restrict__ F0,
    float* __restrict__ out, _Float16* __restrict__ outb,
    float* __restrict__ sums) {
  int n = blockIdx.x * 256 + threadIdx.x;
  if (n >= NN) return;
  float x[DF];
  const float4* xr = reinterpret_cast<const float4*>(x_t + (size_t)n * DF);
#pragma unroll
  for (int q = 0; q < 8; ++q) {
    float4 v = xr[q];
    x[4*q+0]=v.x; x[4*q+1]=v.y; x[4*q+2]=v.z; x[4*q+3]=v.w;
  }
  float4* orow = reinterpret_cast<float4*>(out + (size_t)n * DF);
  _Float16* ob = outb + (size_t)n * DF;
  float s = 0.f;
#pragma unroll
  for (int q = 0; q < 8; ++q) {
    float4 acc = {0.f, 0.f, 0.f, 0.f};
#pragma unroll
    for (int i = 0; i < DF; ++i) {
      float xi = x[i];
      acc.x = fmaf(xi, F0[i*DF + 4*q+0], acc.x);
      acc.y = fmaf(xi, F0[i*DF + 4*q+1], acc.y);
      acc.z = fmaf(xi, F0[i*DF + 4*q+2], acc.z);
      acc.w = fmaf(xi, F0[i*DF + 4*q+3], acc.w);
    }
    orow[q] = acc;
    s += acc.x + acc.y + acc.z + acc.w;
    half4v pk = {(_Float16)acc.x, (_Float16)acc.y, (_Float16)acc.z, (_Float16)acc.w};
    *(half4v*)(ob + 4*q) = pk;
  }
  sums[n] = s;
}

// ------- pre (f16 MFMA): ABh[n][128] = [xs|out|0] @ Wpre -------
__global__ __launch_bounds__(256, 4) void pre_kernel(
    const float* __restrict__ x_s, const _Float16* __restrict__ outb,
    const _Float16* __restrict__ WpreT, _Float16* __restrict__ ABh) {
  __shared__ _Float16 wlds[128][72];
  __shared__ _Float16 st[64][136];  // C-frag transpose staging
  int tid = threadIdx.x;
  for (int t = tid; t < 1024; t += 256) {
    int colr = t >> 3, kc = t & 7;
    *(half8*)(&wlds[colr][kc * 8]) = *(const half8*)(WpreT + colr * 64 + kc * 8);
  }
  __syncthreads();

  int lcol = tid & 15, kgrp = (tid >> 4) & 3, wid = tid >> 6;
  int nodebase = blockIdx.x * 64 + wid * 16;
  int nodeA = nodebase + lcol;

  half8 a0 = {}, a1 = {};
  if (nodeA < NN) {
    const _Float16* obp = outb + (size_t)nodeA * DF;
    if (kgrp < 2) {
      const float4* p = (const float4*)(x_s + (size_t)nodeA * SF);
      float4 v0 = p[kgrp * 2], v1 = p[kgrp * 2 + 1];
      a0[0]=(_Float16)v0.x; a0[1]=(_Float16)v0.y;
      a0[2]=(_Float16)v0.z; a0[3]=(_Float16)v0.w;
      a0[4]=(_Float16)v1.x; a0[5]=(_Float16)v1.y;
      a0[6]=(_Float16)v1.z; a0[7]=(_Float16)v1.w;
      a1 = *(const half8*)(obp + 16 + kgrp * 8);
    } else if (kgrp == 2) {
      a0 = *(const half8*)(obp + 0);
    } else {
      a0 = *(const half8*)(obp + 8);
    }
  }

  floatx4 acc[8];
#pragma unroll
  for (int nt = 0; nt < 8; ++nt) {
    half8 b0 = *(const half8*)(&wlds[nt * 16 + lcol][kgrp * 8]);
    half8 b1v = *(const half8*)(&wlds[nt * 16 + lcol][32 + kgrp * 8]);
    floatx4 c = {0.f, 0.f, 0.f, 0.f};
    c = __builtin_amdgcn_mfma_f32_16x16x32_f16(a0, b0, c, 0, 0, 0);
    c = __builtin_amdgcn_mfma_f32_16x16x32_f16(a1, b1v, c, 0, 0, 0);
    acc[nt] = c;
  }

  // stage C-frags in LDS (wave-local rows), then coalesced 64B global writes
#pragma unroll
  for (int nt = 0; nt < 8; ++nt) {
#pragma unroll
    for (int rr = 0; rr < 4; ++rr)
      st[wid * 16 + kgrp * 4 + rr][nt * 16 + lcol] = (_Float16)acc[nt][rr];
  }
  // wave w reads nodes 16w..16w+15 (its own writes; same-wave LDS is ordered)
  int nl = tid >> 2, q = tid & 3;
  int node = blockIdx.x * 64 + nl;
  if (node < NN) {
    _Float16* dst = ABh + (size_t)node * 128 + q * 32;
#pragma unroll
    for (int s = 0; s < 4; ++s)
      *(half8*)(dst + s * 8) = *(const half8*)(&st[nl][q * 32 + s * 8]);
  }
}

// ---------------- edge MLP (f16 MFMA, fp8 h-tile) + owner epilogue ----------------
__global__ __launch_bounds__(256, 5) void edge_kernel(
    const _Float16* __restrict__ ABh, const _Float16* __restrict__ outb,
    const float* __restrict__ sums, const char* __restrict__ recs,
    const float* __restrict__ b1, const float* __restrict__ b2,
    const _Float16* __restrict__ w2pk, const _Float16* __restrict__ w1epk,
    float* __restrict__ scattered) {
  // One 72B-stride row per edge, two views with IDENTICAL row ranges:
  //   fp8 h view: bytes [r*72, r*72+64)   (phases 0-2)
  //   f16 sh view: halves [r*36, r*36+32) (phases 3-4)
  // -> all of phases 0-3 are wave-local (rows 64w..64w+63); no mid barrier.
  // launch_bounds(256,5): 102 arch-reg budget fits the ~96-reg working set
  // (round-14's (256,8) forced 64 -> 175MB/dispatch scratch spills).
  __shared__ unsigned short lds[256 * 36];  // 18432 B
  __shared__ int scol[256];
  __shared__ unsigned char l0[256], lenm1[256];
  __shared__ int wbase[4];
  __shared__ int cnt;

  unsigned char* hb = (unsigned char*)lds;
  _Float16* shh = (_Float16*)lds;

  int tid = threadIdx.x;
  int bbase = blockIdx.x * 256;
  int i = bbase + tid;  // NE % 256 == 0: always valid
  if (tid == 0) cnt = 0;
  int lcol = tid & 15, kgrp = (tid >> 4) & 3, wid = tid >> 6;
  int lane = tid & 63;

  // load packed record {r, c, ea[8] f16}
  const int2* rp = (const int2*)(recs + (size_t)i * 24);
  int2 ra = rp[0], rb = rp[1], rd = rp[2];
  int r = ra.x;
  int c = ra.y;
  int4 eai = {rb.x, rb.y, rd.x, rd.y};
  scol[tid] = c;
  float s_r = sums[r], s_c = sums[c];

  // EARLY-ISSUE: stage A[r] and B[c] halves (128B each) into registers so
  // the HBM/L3 latency hides under phase-0's shuffles + MFMAs.
  half8 Ar[8], Bc[8];
  {
    const half8* arp = (const half8*)(ABh + (size_t)r * 128);
    const half8* bcp = (const half8*)(ABh + (size_t)c * 128 + 64);
#pragma unroll
    for (int q = 0; q < 8; ++q) { Ar[q] = arp[q]; Bc[q] = bcp[q]; }
  }

  float b2c0 = b2[lcol], b2c1 = b2[16 + lcol];

  // ---- phase 0: eaw^T = W1e^T @ ea via swapped MFMA -> fp8 dword writes ----
  const _Float16* wep = w1epk + (size_t)lane * 32;
  half8 wA0 = *(const half8*)(wep);
  half8 wA1 = *(const half8*)(wep + 8);
  half8 wA2 = *(const half8*)(wep + 16);
  half8 wA3 = *(const half8*)(wep + 24);
  const float4* b1f4 = (const float4*)b1;
  float4 b1q0 = b1f4[0 + kgrp];
  float4 b1q1 = b1f4[4 + kgrp];
  float4 b1q2 = b1f4[8 + kgrp];
  float4 b1q3 = b1f4[12 + kgrp];
  bool lo16 = lane < 16;
#pragma unroll
  for (int g = 0; g < 4; ++g) {
    int src = g * 16 + lcol;
    int4 t;
    t.x = __shfl(eai.x, src, 64);
    t.y = __shfl(eai.y, src, 64);
    t.z = __shfl(eai.z, src, 64);
    t.w = __shfl(eai.w, src, 64);
    half8 zz = {};
    half8 bg = lo16 ? __builtin_bit_cast(half8, t) : zz;
    int erow = wid * 64 + g * 16 + lcol;
    unsigned char* hrow = hb + erow * 72 + kgrp * 4;
    {
      floatx4 cc = {b1q0.x, b1q0.y, b1q0.z, b1q0.w};
      cc = __builtin_amdgcn_mfma_f32_16x16x32_f16(wA0, bg, cc, 0, 0, 0);
      *(unsigned int*)(hrow + 0)  = pk_fp8x4(cc[0], cc[1], cc[2], cc[3]);
    }
    {
      floatx4 cc = {b1q1.x, b1q1.y, b1q1.z, b1q1.w};
      cc = __builtin_amdgcn_mfma_f32_16x16x32_f16(wA1, bg, cc, 0, 0, 0);
      *(unsigned int*)(hrow + 16) = pk_fp8x4(cc[0], cc[1], cc[2], cc[3]);
    }
    {
      floatx4 cc = {b1q2.x, b1q2.y, b1q2.z, b1q2.w};
      cc = __builtin_amdgcn_mfma_f32_16x16x32_f16(wA2, bg, cc, 0, 0, 0);
      *(unsigned int*)(hrow + 32) = pk_fp8x4(cc[0], cc[1], cc[2], cc[3]);
    }
    {
      floatx4 cc = {b1q3.x, b1q3.y, b1q3.z, b1q3.w};
      cc = __builtin_amdgcn_mfma_f32_16x16x32_f16(wA3, bg, cc, 0, 0, 0);
      *(unsigned int*)(hrow + 48) = pk_fp8x4(cc[0], cc[1], cc[2], cc[3]);
    }
  }

  // ---- phase 1: h = relu(A[r] + B[c] + eaw), fp8 RMW on own row ----
#pragma unroll
  for (int q = 0; q < 8; ++q) {
    unsigned char* p = hb + tid * 72 + q * 8;
    uint2 w = *(const uint2*)p;
    half8 wf = oct2h8(w);
    half8 s = Ar[q] + Bc[q] + wf;
    short8 sb = __builtin_bit_cast(short8, s);
    short8 m = sb >> 15;
    sb = sb & ~m;  // relu: zero negatives (and -0)
    half8 sr = __builtin_bit_cast(half8, sb);
    uint2 o;
    o.x = pk_fp8x4((float)sr[0], (float)sr[1], (float)sr[2], (float)sr[3]);
    o.y = pk_fp8x4((float)sr[4], (float)sr[5], (float)sr[6], (float)sr[7]);
    *(uint2*)p = o;
  }

  // ---- phase 2: layer-2 MFMA, 4 groups of 16 edges per wave ----
  const _Float16* wpp = w2pk + (size_t)lane * 32;
  half8 w2f00 = *(const half8*)(wpp);
  half8 w2f01 = *(const half8*)(wpp + 8);
  half8 w2f10 = *(const half8*)(wpp + 16);
  half8 w2f11 = *(const half8*)(wpp + 24);
  floatx4 acc[4][2];
#pragma unroll
  for (int g = 0; g < 4; ++g) {
    int erow = wid * 64 + g * 16 + lcol;
    const unsigned char* hr = hb + erow * 72;
    half8 a0 = oct2h8(*(const uint2*)(hr + kgrp * 8));
    half8 a1 = oct2h8(*(const uint2*)(hr + 32 + kgrp * 8));
    floatx4 c0 = {b2c0, b2c0, b2c0, b2c0};
    floatx4 c1 = {b2c1, b2c1, b2c1, b2c1};
    c0 = __builtin_amdgcn_mfma_f32_16x16x32_f16(a0, w2f00, c0, 0, 0, 0);
    c0 = __builtin_amdgcn_mfma_f32_16x16x32_f16(a1, w2f10, c0, 0, 0, 0);
    c1 = __builtin_amdgcn_mfma_f32_16x16x32_f16(a0, w2f01, c1, 0, 0, 0);
    c1 = __builtin_amdgcn_mfma_f32_16x16x32_f16(a1, w2f11, c1, 0, 0, 0);
    acc[g][0] = c0;
    acc[g][1] = c1;
  }

  // EARLY-ISSUE: outb rows for the epilogue.
  half8 Or[4], Oc[4];
  {
    const half8* orp = (const half8*)(outb + (size_t)r * DF);
    const half8* ocp = (const half8*)(outb + (size_t)c * DF);
#pragma unroll
    for (int q = 0; q < 4; ++q) { Or[q] = orp[q]; Oc[q] = ocp[q]; }
  }

  // ---- phase 3a: dump o (C-frags) to f16 sh view (same wave-local rows;
  //      acc data-dependency orders these after phase-2 LDS reads) ----
#pragma unroll
  for (int g = 0; g < 4; ++g) {
#pragma unroll
    for (int rr = 0; rr < 4; ++rr) {
      int e = wid * 64 + g * 16 + kgrp * 4 + rr;
      shh[e * 36 + lcol]      = (_Float16)acc[g][0][rr];
      shh[e * 36 + 16 + lcol] = (_Float16)acc[g][1][rr];
    }
  }

  // ---- phase 3b: owner-centric norm + mask + shift (wave-local) ----
  {
    float o2[32];
    float nsq = 0.f;
#pragma unroll
    for (int m = 0; m < 8; ++m) {
      uint2 w = *(const uint2*)(hb + tid * 72 + m * 8);
      half4v hv = __builtin_bit_cast(half4v, w);
#pragma unroll
      for (int jj = 0; jj < 4; ++jj) {
        float v = (float)hv[jj];
        o2[m * 4 + jj] = v;
        nsq = fmaf(v, v, nsq);
      }
    }
    float ms = (nsq > 0.f) ? rsqrtf(nsq) : 0.f;
    if (s_r == 0.f && s_c == 0.f) ms = 0.f;
#pragma unroll
    for (int m = 0; m < 8; ++m) {
      int q = m >> 1, base = (m & 1) * 4;
      float f0 = ((float)Oc[q][base+0] - (float)Or[q][base+0]) * o2[m*4+0] * ms;
      float f1 = ((float)Oc[q][base+1] - (float)Or[q][base+1]) * o2[m*4+1] * ms;
      float f2 = ((float)Oc[q][base+2] - (float)Or[q][base+2]) * o2[m*4+2] * ms;
      float f3 = ((float)Oc[q][base+3] - (float)Or[q][base+3]) * o2[m*4+3] * ms;
      half2v p0 = pkrtz2(f0, f1);
      half2v p1 = pkrtz2(f2, f3);
      uint2 o;
      o.x = __builtin_bit_cast(unsigned int, p0);
      o.y = __builtin_bit_cast(unsigned int, p1);
      *(uint2*)(hb + tid * 72 + m * 8) = o;
    }
  }
  __syncthreads();  // cross-wave: sh rows + scol + cnt now visible

  // ---- phase 4: segmented reduce over sorted-col runs ----
  int c_self = scol[tid];
  bool head = (tid == 0 || scol[tid - 1] != c_self);
  unsigned long long m = __ballot(head);
  if (lane == 0) wbase[wid] = atomicAdd(&cnt, (int)__popcll(m));
  __syncthreads();
  if (head) {
    int idx = wbase[wid] + (int)__popcll(m & ((1ull << lane) - 1ull));
    int t1 = tid + 1;
    while (t1 < 256 && scol[t1] == c_self) ++t1;
    l0[idx] = (unsigned char)tid;
    lenm1[idx] = (unsigned char)(t1 - tid - 1);
  }
  __syncthreads();
  int nr = cnt;
  for (int task = tid; task < nr * 32; task += 256) {
    int rid = task >> 5, j = task & 31;
    int t0 = l0[rid];
    int t1 = t0 + lenm1[rid] + 1;
    float s = 0.f;
    for (int t = t0; t < t1; ++t) s += (float)shh[t * 36 + j];
    unsafeAtomicAdd(&scattered[(size_t)scol[t0] * DF + j], s);
  }
}

// --- node update (in place): out += scattered @ Fk; outb/sums; clear sc ---
__global__ __launch_bounds__(256) void node_kernel(
    float* __restrict__ out, float* __restrict__ scattered,
    const float* __restrict__ Fk, _Float16* __restrict__ outb,
    float* __restrict__ sums) {
  int n = blockIdx.x * 256 + threadIdx.x;
  if (n >= NN) return;
  float s[DF];
  float4* sp = reinterpret_cast<float4*>(scattered + (size_t)n * DF);
#pragma unroll
  for (int q = 0; q < 8; ++q) {
    float4 v = sp[q];
    s[4*q+0]=v.x; s[4*q+1]=v.y; s[4*q+2]=v.z; s[4*q+3]=v.w;
  }
  float4* op = reinterpret_cast<float4*>(out + (size_t)n * DF);
  _Float16* ob = outb + (size_t)n * DF;
  float ssum = 0.f;
#pragma unroll
  for (int q = 0; q < 8; ++q) {
    float4 acc = op[q];
#pragma unroll
    for (int i = 0; i < DF; ++i) {
      float si = s[i];
      acc.x = fmaf(si, Fk[i*DF + 4*q+0], acc.x);
      acc.y = fmaf(si, Fk[i*DF + 4*q+1], acc.y);
      acc.z = fmaf(si, Fk[i*DF + 4*q+2], acc.z);
      acc.w = fmaf(si, Fk[i*DF + 4*q+3], acc.w);
    }
    op[q] = acc;
    ssum += acc.x + acc.y + acc.z + acc.w;
    half4v pk = {(_Float16)acc.x, (_Float16)acc.y, (_Float16)acc.z, (_Float16)acc.w};
    *(half4v*)(ob + 4*q) = pk;
  }
  sums[n] = ssum;
  float4 z = {0.f, 0.f, 0.f, 0.f};
#pragma unroll
  for (int q = 0; q < 8; ++q) sp[q] = z;
}

extern "C" void kernel_launch(void* const* d_in, const int* in_sizes, int n_in,
                              void* d_out, int out_size, void* d_ws, size_t ws_size,
                              hipStream_t stream) {
  const float* x_s = (const float*)d_in[0];
  const float* x_t = (const float*)d_in[1];
  const int*   ei  = (const int*)d_in[2];
  const float* ea  = (const float*)d_in[3];
  const float* W1  = (const float*)d_in[4];
  const float* b1  = (const float*)d_in[5];
  const float* W2  = (const float*)d_in[6];
  const float* b2  = (const float*)d_in[7];
  const float* F   = (const float*)d_in[8];

  float* out = (float*)d_out;
  char* ws = (char*)d_ws;
  float*     scattered = (float*)(ws);                  // 12.8 MB
  _Float16*  ABh       = (_Float16*)(ws + 12800000);    // 25.6 MB
  _Float16*  outb      = (_Float16*)(ws + 38400000);    // 6.4 MB
  float*     sums      = (float*)(ws + 44800000);       // 0.4 MB
  char*      recs      = (char*)(ws + 45200000);        // 38.4 MB (24B/edge)
  int*       deg       = (int*)(ws + 83600000);         // 0.4 MB
  int*       cur       = (int*)(ws + 84000000);         // 0.4 MB
  int*       bsums     = (int*)(ws + 84400000);         // 4 KB
  _Float16*  WpreT     = (_Float16*)(ws + 84410000);    // 16 KB
  _Float16*  w2pk      = (_Float16*)(ws + 84430000);    // 4 KB
  _Float16*  w1epk     = (_Float16*)(ws + 84440000);    // 4 KB

  dim3 blk(256);
  dim3 grid_e(NE / 256);          // 6250, exact
  dim3 grid_n((NN + 255) / 256);  // 391
  dim3 grid_p((NN + 63) / 64);    // 1563
  int nscan = (NN + 1023) / 1024; // 98

  setup_kernel<<<3125, blk, 0, stream>>>(W1, W2, WpreT, w2pk, w1epk,
                                         (float4*)scattered, deg);
  hist_kernel<<<grid_e, blk, 0, stream>>>(ei, deg);
  scan1_kernel<<<nscan, blk, 0, stream>>>(deg, cur, bsums);
  scan3_kernel<<<grid_n, blk, 0, stream>>>(cur, bsums);
  fill_kernel<<<grid_e, blk, 0, stream>>>(ei, ea, cur, recs);

  init_kernel<<<grid_n, blk, 0, stream>>>(x_t, F, out, outb, sums);

  for (int k = 0; k < 2; ++k) {
    pre_kernel<<<grid_p, blk, 0, stream>>>(x_s, outb, WpreT, ABh);
    edge_kernel<<<grid_e, blk, 0, stream>>>(ABh, outb, sums, recs, b1, b2,
                                            w2pk, w1epk, scattered);
    node_kernel<<<grid_n, blk, 0, stream>>>(out, scattered,
                                            F + (size_t)(k + 1) * DF * DF,
                                            outb, sums);
  }
}

// Round 16
// 441.842 us; speedup vs baseline: 1.3653x; 1.0615x over previous
//
#include <hip/hip_runtime.h>

#define NN 100000
#define NE 1600000
#define SF 16
#define DF 32
#define EFT 8
#define HF 64

typedef __attribute__((ext_vector_type(8))) _Float16 half8;
typedef __attribute__((ext_vector_type(4))) _Float16 half4v;
typedef __attribute__((ext_vector_type(8))) short short8;
typedef __attribute__((ext_vector_type(4))) float floatx4;

// swizzled half-index into the [256][64] h tile (128B rows, 16B-granule XOR)
__device__ inline int hswz(int row, int halfoff) {
  int gran = halfoff >> 3, sub = halfoff & 7;
  return row * 64 + ((gran ^ (row & 7)) << 3) + sub;
}

// ---------------- CSR build ----------------
__global__ __launch_bounds__(256) void hist_kernel(const int* __restrict__ ei,
                                                   int* __restrict__ deg) {
  int e = blockIdx.x * 256 + threadIdx.x;
  if (e < NE) atomicAdd(&deg[ei[NE + e]], 1);
}

__global__ __launch_bounds__(256) void scan1_kernel(const int* __restrict__ deg,
                                                    int* __restrict__ cur,
                                                    int* __restrict__ bsums) {
  __shared__ int ts[256];
  int tid = threadIdx.x;
  int base = blockIdx.x * 1024 + tid * 4;
  int v[4];
#pragma unroll
  for (int q = 0; q < 4; ++q) v[q] = (base + q < NN) ? deg[base + q] : 0;
  int s = v[0] + v[1] + v[2] + v[3];
  ts[tid] = s;
  __syncthreads();
  for (int off = 1; off < 256; off <<= 1) {
    int t = (tid >= off) ? ts[tid - off] : 0;
    __syncthreads();
    ts[tid] += t;
    __syncthreads();
  }
  int excl = ts[tid] - s;
  if (tid == 255) bsums[blockIdx.x] = ts[255];
  int run = excl;
#pragma unroll
  for (int q = 0; q < 4; ++q) {
    if (base + q < NN) cur[base + q] = run;
    run += v[q];
  }
}

__global__ __launch_bounds__(256) void scan3_kernel(int* __restrict__ cur,
                                                    const int* __restrict__ bsums) {
  int i = blockIdx.x * 256 + threadIdx.x;
  int g = blockIdx.x >> 2;
  int pref = 0;
  for (int q = 0; q < g; ++q) pref += bsums[q];
  if (i < NN) cur[i] += pref;
}

// ---- setup: zero scattered+deg; pack WpreT, W2 frags, W1e^T frags (f16) ----
__global__ __launch_bounds__(256) void setup_kernel(
    const float* __restrict__ W1, const float* __restrict__ W2,
    _Float16* __restrict__ WpreT, _Float16* __restrict__ w2pk,
    _Float16* __restrict__ w1epk,
    float4* __restrict__ scattered4, int* __restrict__ deg) {
  int gid = blockIdx.x * 256 + threadIdx.x;
  if (gid < 800000) {
    float4 z = {0.f, 0.f, 0.f, 0.f};
    scattered4[gid] = z;
  }
  if (gid < NN) deg[gid] = 0;
  if (gid < 128 * 64) {
    int col = gid >> 6, k = gid & 63;
    int j = col & 63;
    bool bh = col >= 64;
    float v = 0.f;
    if (k < 16) v = W1[((bh ? 16 : 0) + k) * HF + j];
    else if (k < 48) v = W1[((bh ? 64 : 32) + (k - 16)) * HF + j];
    WpreT[gid] = (_Float16)v;
  }
  if (gid < 2048) {
    // W2 B-frags: lane holds col = nt*16+lcol, k = kt*32 + kgrp*8 + q
    int lane = gid >> 5, idx = gid & 31;
    int kt = idx >> 4, nt = (idx >> 3) & 1, q = idx & 7;
    int kgrp = (lane >> 4) & 3, lcol = lane & 15;
    w2pk[gid] = (_Float16)W2[(kt * 32 + kgrp * 8 + q) * DF + nt * 16 + lcol];
  } else if (gid < 4096) {
    // W1e^T A-frags: lane<16 holds row j=lane (within jblk), k=t (k>=8 -> 0)
    int id = gid - 2048;  // lane*32 + jblk*8 + t
    int lane = id >> 5, idx = id & 31;
    int jblk = idx >> 3, t = idx & 7;
    float v = (lane < 16) ? W1[(96 + t) * HF + jblk * 16 + lane] : 0.f;
    w1epk[id] = (_Float16)v;
  }
}

// ---- fill: packed 24B sorted records {int r, int c, half ea[8]} ----
__global__ __launch_bounds__(256) void fill_kernel(
    const int* __restrict__ ei, const float* __restrict__ ea,
    int* __restrict__ cur, char* __restrict__ recs) {
  int e = blockIdx.x * 256 + threadIdx.x;
  int r = ei[e];
  int c = ei[NE + e];
  int pos = atomicAdd(&cur[c], 1);
  const float4* p = (const float4*)(ea + (size_t)e * EFT);
  float4 v0 = p[0], v1 = p[1];
  union { _Float16 h[2]; int i; } p01, p23, p45, p67;
  p01.h[0] = (_Float16)v0.x; p01.h[1] = (_Float16)v0.y;
  p23.h[0] = (_Float16)v0.z; p23.h[1] = (_Float16)v0.w;
  p45.h[0] = (_Float16)v1.x; p45.h[1] = (_Float16)v1.y;
  p67.h[0] = (_Float16)v1.z; p67.h[1] = (_Float16)v1.w;
  int2* rp = (int2*)(recs + (size_t)pos * 24);
  int2 a = {r, c};
  int2 b = {p01.i, p23.i};
  int2 d = {p45.i, p67.i};
  rp[0] = a; rp[1] = b; rp[2] = d;
}

// ---------------- init: out = x_t @ F[0]; also outb(f16), sums ----------------
__global__ __launch_bounds__(256) void init_kernel(
    const float* __restrict__ x_t, const float* __restrict__ F0,
    float* __restrict__ out, _Float16* __restrict__ outb,
    float* __restrict__ sums) {
  int n = blockIdx.x * 256 + threadIdx.x;
  if (n >= NN) return;
  float x[DF];
  const float4* xr = reinterpret_cast<const float4*>(x_t + (size_t)n * DF);
#pragma unroll
  for (int q = 0; q < 8; ++q) {
    float4 v = xr[q];
    x[4*q+0]=v.x; x[4*q+1]=v.y; x[4*q+2]=v.z; x[4*q+3]=v.w;
  }
  float4* orow = reinterpret_cast<float4*>(out + (size_t)n * DF);
  _Float16* ob = outb + (size_t)n * DF;
  float s = 0.f;
#pragma unroll
  for (int q = 0; q < 8; ++q) {
    float4 acc = {0.f, 0.f, 0.f, 0.f};
#pragma unroll
    for (int i = 0; i < DF; ++i) {
      float xi = x[i];
      acc.x = fmaf(xi, F0[i*DF + 4*q+0], acc.x);
      acc.y = fmaf(xi, F0[i*DF + 4*q+1], acc.y);
      acc.z = fmaf(xi, F0[i*DF + 4*q+2], acc.z);
      acc.w = fmaf(xi, F0[i*DF + 4*q+3], acc.w);
    }
    orow[q] = acc;
    s += acc.x + acc.y + acc.z + acc.w;
    half4v pk = {(_Float16)acc.x, (_Float16)acc.y, (_Float16)acc.z, (_Float16)acc.w};
    *(half4v*)(ob + 4*q) = pk;
  }
  sums[n] = s;
}

// ------- pre (f16 MFMA): ABh[n][128] = [xs|out|0] @ Wpre -------
__global__ __launch_bounds__(256, 4) void pre_kernel(
    const float* __restrict__ x_s, const _Float16* __restrict__ outb,
    const _Float16* __restrict__ WpreT, _Float16* __restrict__ ABh) {
  __shared__ _Float16 wlds[128][72];
  int tid = threadIdx.x;
  for (int t = tid; t < 1024; t += 256) {
    int colr = t >> 3, kc = t & 7;
    *(half8*)(&wlds[colr][kc * 8]) = *(const half8*)(WpreT + colr * 64 + kc * 8);
  }
  __syncthreads();

  int lcol = tid & 15, kgrp = (tid >> 4) & 3, wid = tid >> 6;
  int nodebase = blockIdx.x * 64 + wid * 16;
  int nodeA = nodebase + lcol;

  half8 a0 = {}, a1 = {};
  if (nodeA < NN) {
    const _Float16* obp = outb + (size_t)nodeA * DF;
    if (kgrp < 2) {
      const float4* p = (const float4*)(x_s + (size_t)nodeA * SF);
      float4 v0 = p[kgrp * 2], v1 = p[kgrp * 2 + 1];
      a0[0]=(_Float16)v0.x; a0[1]=(_Float16)v0.y;
      a0[2]=(_Float16)v0.z; a0[3]=(_Float16)v0.w;
      a0[4]=(_Float16)v1.x; a0[5]=(_Float16)v1.y;
      a0[6]=(_Float16)v1.z; a0[7]=(_Float16)v1.w;
      a1 = *(const half8*)(obp + 16 + kgrp * 8);
    } else if (kgrp == 2) {
      a0 = *(const half8*)(obp + 0);
    } else {
      a0 = *(const half8*)(obp + 8);
    }
  }

  floatx4 acc[8];
#pragma unroll
  for (int nt = 0; nt < 8; ++nt) {
    half8 b0 = *(const half8*)(&wlds[nt * 16 + lcol][kgrp * 8]);
    half8 b1v = *(const half8*)(&wlds[nt * 16 + lcol][32 + kgrp * 8]);
    floatx4 c = {0.f, 0.f, 0.f, 0.f};
    c = __builtin_amdgcn_mfma_f32_16x16x32_f16(a0, b0, c, 0, 0, 0);
    c = __builtin_amdgcn_mfma_f32_16x16x32_f16(a1, b1v, c, 0, 0, 0);
    acc[nt] = c;
  }

#pragma unroll
  for (int rr = 0; rr < 4; ++rr) {
    int node = nodebase + kgrp * 4 + rr;
    if (node < NN) {
      _Float16* dst = ABh + (size_t)node * 128;
#pragma unroll
      for (int nt = 0; nt < 8; ++nt)
        dst[nt * 16 + lcol] = (_Float16)acc[nt][rr];
    }
  }
}

// ---------------- edge MLP (f16 MFMA) + owner-centric epilogue ----------------
__global__ __launch_bounds__(256, 4) void edge_kernel(
    const _Float16* __restrict__ ABh, const _Float16* __restrict__ outb,
    const float* __restrict__ sums, const char* __restrict__ recs,
    const float* __restrict__ b1, const float* __restrict__ b2,
    const _Float16* __restrict__ w2pk, const _Float16* __restrict__ w1epk,
    float* __restrict__ scattered) {
  // h: [256][64] halves, 128B rows, XOR-swizzled granules (32768 B)
  // sh: [256] rows of 33 f32 (33792 B) -> union 33792 B
  __shared__ union { _Float16 h[256 * 64]; float sh[256 * 33]; } u;
  __shared__ int scol[256];
  __shared__ unsigned short l0[256], l1[256];
  __shared__ int wbase[4];
  __shared__ int cnt;

  int tid = threadIdx.x;
  int bbase = blockIdx.x * 256;
  int i = bbase + tid;  // NE % 256 == 0: always valid
  if (tid == 0) cnt = 0;
  int lcol = tid & 15, kgrp = (tid >> 4) & 3, wid = tid >> 6;
  int lane = tid & 63;

  // load packed record {r, c, ea[8] f16}
  const int2* rp = (const int2*)(recs + (size_t)i * 24);
  int2 ra = rp[0], rb = rp[1], rd = rp[2];
  int r = ra.x;
  int c = ra.y;
  int4 eai = {rb.x, rb.y, rd.x, rd.y};
  scol[tid] = c;
  float s_r = sums[r], s_c = sums[c];

  // EARLY-ISSUE: stage A[r] and B[c] halves (128B each) into registers so
  // the HBM/L3 latency hides under phase-0's shuffles + MFMAs.
  half8 Ar[8], Bc[8];
  {
    const half8* arp = (const half8*)(ABh + (size_t)r * 128);
    const half8* bcp = (const half8*)(ABh + (size_t)c * 128 + 64);
#pragma unroll
    for (int q = 0; q < 8; ++q) { Ar[q] = arp[q]; Bc[q] = bcp[q]; }
  }

  float b2c0 = b2[lcol], b2c1 = b2[16 + lcol];

  // ---- phase 0: eaw^T = W1e^T @ ea via swapped MFMA -> swizzled half4 writes ----
  const _Float16* wep = w1epk + (size_t)lane * 32;
  half8 wA0 = *(const half8*)(wep);
  half8 wA1 = *(const half8*)(wep + 8);
  half8 wA2 = *(const half8*)(wep + 16);
  half8 wA3 = *(const half8*)(wep + 24);
  const float4* b1f4 = (const float4*)b1;
  float4 b1q0 = b1f4[0 + kgrp];
  float4 b1q1 = b1f4[4 + kgrp];
  float4 b1q2 = b1f4[8 + kgrp];
  float4 b1q3 = b1f4[12 + kgrp];
  bool lo16 = lane < 16;
#pragma unroll
  for (int g = 0; g < 4; ++g) {
    int src = g * 16 + lcol;
    int4 t;
    t.x = __shfl(eai.x, src, 64);
    t.y = __shfl(eai.y, src, 64);
    t.z = __shfl(eai.z, src, 64);
    t.w = __shfl(eai.w, src, 64);
    half8 zz = {};
    half8 bg = lo16 ? __builtin_bit_cast(half8, t) : zz;
    int erow = wid * 64 + g * 16 + lcol;
    {
      floatx4 cc = {b1q0.x, b1q0.y, b1q0.z, b1q0.w};
      cc = __builtin_amdgcn_mfma_f32_16x16x32_f16(wA0, bg, cc, 0, 0, 0);
      half4v h4 = {(_Float16)cc[0], (_Float16)cc[1], (_Float16)cc[2], (_Float16)cc[3]};
      *(half4v*)(&u.h[hswz(erow, 0 * 16 + kgrp * 4)]) = h4;
    }
    {
      floatx4 cc = {b1q1.x, b1q1.y, b1q1.z, b1q1.w};
      cc = __builtin_amdgcn_mfma_f32_16x16x32_f16(wA1, bg, cc, 0, 0, 0);
      half4v h4 = {(_Float16)cc[0], (_Float16)cc[1], (_Float16)cc[2], (_Float16)cc[3]};
      *(half4v*)(&u.h[hswz(erow, 1 * 16 + kgrp * 4)]) = h4;
    }
    {
      floatx4 cc = {b1q2.x, b1q2.y, b1q2.z, b1q2.w};
      cc = __builtin_amdgcn_mfma_f32_16x16x32_f16(wA2, bg, cc, 0, 0, 0);
      half4v h4 = {(_Float16)cc[0], (_Float16)cc[1], (_Float16)cc[2], (_Float16)cc[3]};
      *(half4v*)(&u.h[hswz(erow, 2 * 16 + kgrp * 4)]) = h4;
    }
    {
      floatx4 cc = {b1q3.x, b1q3.y, b1q3.z, b1q3.w};
      cc = __builtin_amdgcn_mfma_f32_16x16x32_f16(wA3, bg, cc, 0, 0, 0);
      half4v h4 = {(_Float16)cc[0], (_Float16)cc[1], (_Float16)cc[2], (_Float16)cc[3]};
      *(half4v*)(&u.h[hswz(erow, 3 * 16 + kgrp * 4)]) = h4;
    }
  }
  // phases 0-2 touch only this wave's h rows: wave-local, no block barrier

  // ---- phase 1: h = relu(A[r] + B[c] + eaw) packed f16, RMW on own row ----
#pragma unroll
  for (int q = 0; q < 8; ++q) {
    int idx = hswz(tid, q * 8);
    half8 w = *(const half8*)(&u.h[idx]);
    half8 s = Ar[q] + Bc[q] + w;
    short8 sb = __builtin_bit_cast(short8, s);
    short8 m = sb >> 15;
    sb = sb & ~m;  // relu: zero negatives (and -0)
    *(short8*)(&u.h[idx]) = sb;
  }

  // ---- phase 2: layer-2 MFMA, 4 groups of 16 edges per wave ----
  const _Float16* wpp = w2pk + (size_t)lane * 32;
  half8 w2f00 = *(const half8*)(wpp);
  half8 w2f01 = *(const half8*)(wpp + 8);
  half8 w2f10 = *(const half8*)(wpp + 16);
  half8 w2f11 = *(const half8*)(wpp + 24);
  floatx4 acc[4][2];
#pragma unroll
  for (int g = 0; g < 4; ++g) {
    int erow = wid * 64 + g * 16 + lcol;
    half8 a0 = *(const half8*)(&u.h[hswz(erow, kgrp * 8)]);
    half8 a1 = *(const half8*)(&u.h[hswz(erow, 32 + kgrp * 8)]);
    floatx4 c0 = {b2c0, b2c0, b2c0, b2c0};
    floatx4 c1 = {b2c1, b2c1, b2c1, b2c1};
    c0 = __builtin_amdgcn_mfma_f32_16x16x32_f16(a0, w2f00, c0, 0, 0, 0);
    c0 = __builtin_amdgcn_mfma_f32_16x16x32_f16(a1, w2f10, c0, 0, 0, 0);
    c1 = __builtin_amdgcn_mfma_f32_16x16x32_f16(a0, w2f01, c1, 0, 0, 0);
    c1 = __builtin_amdgcn_mfma_f32_16x16x32_f16(a1, w2f11, c1, 0, 0, 0);
    acc[g][0] = c0;
    acc[g][1] = c1;
  }

  // EARLY-ISSUE: outb rows for the epilogue, overlapping the barrier wait.
  half8 Or[4], Oc[4];
  {
    const half8* orp = (const half8*)(outb + (size_t)r * DF);
    const half8* ocp = (const half8*)(outb + (size_t)c * DF);
#pragma unroll
    for (int q = 0; q < 4; ++q) { Or[q] = orp[q]; Oc[q] = ocp[q]; }
  }

  // RACE FIX: all waves must finish phase-2 h reads before any sh writes
  // (the two union views have different row strides -> cross-wave overlap).
  __syncthreads();

  // ---- phase 3a: dump o (C-frags) to LDS, stride-33 f32 rows ----
#pragma unroll
  for (int g = 0; g < 4; ++g) {
#pragma unroll
    for (int rr = 0; rr < 4; ++rr) {
      int e = wid * 64 + g * 16 + kgrp * 4 + rr;
      u.sh[e * 33 + lcol]      = acc[g][0][rr];
      u.sh[e * 33 + 16 + lcol] = acc[g][1][rr];
    }
  }

  // ---- phase 3b: owner-centric norm + mask + shift (all wave-local) ----
  {
    float o2[32];
    float nsq = 0.f;
#pragma unroll
    for (int j = 0; j < 32; ++j) {
      float v = u.sh[tid * 33 + j];
      o2[j] = v;
      nsq = fmaf(v, v, nsq);
    }
    float ms = (nsq > 0.f) ? rsqrtf(nsq) : 0.f;
    if (s_r == 0.f && s_c == 0.f) ms = 0.f;
#pragma unroll
    for (int q = 0; q < 4; ++q) {
#pragma unroll
      for (int jj = 0; jj < 8; ++jj)
        u.sh[tid * 33 + q * 8 + jj] =
            ((float)Oc[q][jj] - (float)Or[q][jj]) * o2[q * 8 + jj] * ms;
    }
  }
  __syncthreads();  // cross-wave: sh rows + scol + cnt now visible

  // ---- phase 4: segmented reduce over sorted-col runs ----
  int c_self = scol[tid];
  bool head = (tid == 0 || scol[tid - 1] != c_self);
  unsigned long long m = __ballot(head);
  if (lane == 0) wbase[wid] = atomicAdd(&cnt, (int)__popcll(m));
  __syncthreads();
  if (head) {
    int idx = wbase[wid] + (int)__popcll(m & ((1ull << lane) - 1ull));
    int t1 = tid + 1;
    while (t1 < 256 && scol[t1] == c_self) ++t1;
    l0[idx] = (unsigned short)tid;
    l1[idx] = (unsigned short)t1;
  }
  __syncthreads();
  int nr = cnt;
  for (int task = tid; task < nr * 32; task += 256) {
    int rid = task >> 5, j = task & 31;
    int t0 = l0[rid], t1 = l1[rid];
    float s = 0.f;
    for (int t = t0; t < t1; ++t) s += u.sh[t * 33 + j];
    unsafeAtomicAdd(&scattered[(size_t)scol[t0] * DF + j], s);
  }
}

// --- node update (in place): out += scattered @ Fk; outb/sums; clear sc ---
__global__ __launch_bounds__(256) void node_kernel(
    float* __restrict__ out, float* __restrict__ scattered,
    const float* __restrict__ Fk, _Float16* __restrict__ outb,
    float* __restrict__ sums) {
  int n = blockIdx.x * 256 + threadIdx.x;
  if (n >= NN) return;
  float s[DF];
  float4* sp = reinterpret_cast<float4*>(scattered + (size_t)n * DF);
#pragma unroll
  for (int q = 0; q < 8; ++q) {
    float4 v = sp[q];
    s[4*q+0]=v.x; s[4*q+1]=v.y; s[4*q+2]=v.z; s[4*q+3]=v.w;
  }
  float4* op = reinterpret_cast<float4*>(out + (size_t)n * DF);
  _Float16* ob = outb + (size_t)n * DF;
  float ssum = 0.f;
#pragma unroll
  for (int q = 0; q < 8; ++q) {
    float4 acc = op[q];
#pragma unroll
    for (int i = 0; i < DF; ++i) {
      float si = s[i];
      acc.x = fmaf(si, Fk[i*DF + 4*q+0], acc.x);
      acc.y = fmaf(si, Fk[i*DF + 4*q+1], acc.y);
      acc.z = fmaf(si, Fk[i*DF + 4*q+2], acc.z);
      acc.w = fmaf(si, Fk[i*DF + 4*q+3], acc.w);
    }
    op[q] = acc;
    ssum += acc.x + acc.y + acc.z + acc.w;
    half4v pk = {(_Float16)acc.x, (_Float16)acc.y, (_Float16)acc.z, (_Float16)acc.w};
    *(half4v*)(ob + 4*q) = pk;
  }
  sums[n] = ssum;
  float4 z = {0.f, 0.f, 0.f, 0.f};
#pragma unroll
  for (int q = 0; q < 8; ++q) sp[q] = z;
}

extern "C" void kernel_launch(void* const* d_in, const int* in_sizes, int n_in,
                              void* d_out, int out_size, void* d_ws, size_t ws_size,
                              hipStream_t stream) {
  const float* x_s = (const float*)d_in[0];
  const float* x_t = (const float*)d_in[1];
  const int*   ei  = (const int*)d_in[2];
  const float* ea  = (const float*)d_in[3];
  const float* W1  = (const float*)d_in[4];
  const float* b1  = (const float*)d_in[5];
  const float* W2  = (const float*)d_in[6];
  const float* b2  = (const float*)d_in[7];
  const float* F   = (const float*)d_in[8];

  float* out = (float*)d_out;
  char* ws = (char*)d_ws;
  float*     scattered = (float*)(ws);                  // 12.8 MB
  _Float16*  ABh       = (_Float16*)(ws + 12800000);    // 25.6 MB
  _Float16*  outb      = (_Float16*)(ws + 38400000);    // 6.4 MB
  float*     sums      = (float*)(ws + 44800000);       // 0.4 MB
  char*      recs      = (char*)(ws + 45200000);        // 38.4 MB (24B/edge)
  int*       deg       = (int*)(ws + 83600000);         // 0.4 MB
  int*       cur       = (int*)(ws + 84000000);         // 0.4 MB
  int*       bsums     = (int*)(ws + 84400000);         // 4 KB
  _Float16*  WpreT     = (_Float16*)(ws + 84410000);    // 16 KB
  _Float16*  w2pk      = (_Float16*)(ws + 84430000);    // 4 KB
  _Float16*  w1epk     = (_Float16*)(ws + 84440000);    // 4 KB

  dim3 blk(256);
  dim3 grid_e(NE / 256);          // 6250, exact
  dim3 grid_n((NN + 255) / 256);  // 391
  dim3 grid_p((NN + 63) / 64);    // 1563
  int nscan = (NN + 1023) / 1024; // 98

  setup_kernel<<<3125, blk, 0, stream>>>(W1, W2, WpreT, w2pk, w1epk,
                                         (float4*)scattered, deg);
  hist_kernel<<<grid_e, blk, 0, stream>>>(ei, deg);
  scan1_kernel<<<nscan, blk, 0, stream>>>(deg, cur, bsums);
  scan3_kernel<<<grid_n, blk, 0, stream>>>(cur, bsums);
  fill_kernel<<<grid_e, blk, 0, stream>>>(ei, ea, cur, recs);

  init_kernel<<<grid_n, blk, 0, stream>>>(x_t, F, out, outb, sums);

  for (int k = 0; k < 2; ++k) {
    pre_kernel<<<grid_p, blk, 0, stream>>>(x_s, outb, WpreT, ABh);
    edge_kernel<<<grid_e, blk, 0, stream>>>(ABh, outb, sums, recs, b1, b2,
                                            w2pk, w1epk, scattered);
    node_kernel<<<grid_n, blk, 0, stream>>>(out, scattered,
                                            F + (size_t)(k + 1) * DF * DF,
                                            outb, sums);
  }
}

// Round 17
// 431.642 us; speedup vs baseline: 1.3975x; 1.0236x over previous
//
#include <hip/hip_runtime.h>

#define NN 100000
#define NE 1600000
#define SF 16
#define DF 32
#define EFT 8
#define HF 64

typedef __attribute__((ext_vector_type(8))) _Float16 half8;
typedef __attribute__((ext_vector_type(4))) _Float16 half4v;
typedef __attribute__((ext_vector_type(8))) short short8;
typedef __attribute__((ext_vector_type(4))) float floatx4;

// swizzled half-index into the [256][64] h tile (128B rows, 16B-granule XOR)
__device__ inline int hswz(int row, int halfoff) {
  int gran = halfoff >> 3, sub = halfoff & 7;
  return row * 64 + ((gran ^ (row & 7)) << 3) + sub;
}

// ---------------- CSR scan ----------------
__global__ __launch_bounds__(256) void scan1_kernel(const int* __restrict__ deg,
                                                    int* __restrict__ cur,
                                                    int* __restrict__ bsums) {
  __shared__ int ts[256];
  int tid = threadIdx.x;
  int base = blockIdx.x * 1024 + tid * 4;
  int v[4];
#pragma unroll
  for (int q = 0; q < 4; ++q) v[q] = (base + q < NN) ? deg[base + q] : 0;
  int s = v[0] + v[1] + v[2] + v[3];
  ts[tid] = s;
  __syncthreads();
  for (int off = 1; off < 256; off <<= 1) {
    int t = (tid >= off) ? ts[tid - off] : 0;
    __syncthreads();
    ts[tid] += t;
    __syncthreads();
  }
  int excl = ts[tid] - s;
  if (tid == 255) bsums[blockIdx.x] = ts[255];
  int run = excl;
#pragma unroll
  for (int q = 0; q < 4; ++q) {
    if (base + q < NN) cur[base + q] = run;
    run += v[q];
  }
}

__global__ __launch_bounds__(256) void scan3_kernel(int* __restrict__ cur,
                                                    const int* __restrict__ bsums) {
  int i = blockIdx.x * 256 + threadIdx.x;
  int g = blockIdx.x >> 2;
  int pref = 0;
  for (int q = 0; q < g; ++q) pref += bsums[q];
  if (i < NN) cur[i] += pref;
}

// ---- setup (grid 6250): zero scattered; pack tables; hist (deg pre-zeroed) ----
__global__ __launch_bounds__(256) void setup_kernel(
    const int* __restrict__ ei,
    const float* __restrict__ W1, const float* __restrict__ W2,
    _Float16* __restrict__ WpreT, _Float16* __restrict__ w2pk,
    _Float16* __restrict__ w1epk,
    float4* __restrict__ scattered4, int* __restrict__ deg) {
  int gid = blockIdx.x * 256 + threadIdx.x;
  if (gid < 800000) {
    float4 z = {0.f, 0.f, 0.f, 0.f};
    scattered4[gid] = z;
  }
  if (gid < 128 * 64) {
    int col = gid >> 6, k = gid & 63;
    int j = col & 63;
    bool bh = col >= 64;
    float v = 0.f;
    if (k < 16) v = W1[((bh ? 16 : 0) + k) * HF + j];
    else if (k < 48) v = W1[((bh ? 64 : 32) + (k - 16)) * HF + j];
    WpreT[gid] = (_Float16)v;
  }
  if (gid < 2048) {
    // W2 B-frags: lane holds col = nt*16+lcol, k = kt*32 + kgrp*8 + q
    int lane = gid >> 5, idx = gid & 31;
    int kt = idx >> 4, nt = (idx >> 3) & 1, q = idx & 7;
    int kgrp = (lane >> 4) & 3, lcol = lane & 15;
    w2pk[gid] = (_Float16)W2[(kt * 32 + kgrp * 8 + q) * DF + nt * 16 + lcol];
  } else if (gid < 4096) {
    // W1e^T A-frags: lane<16 holds row j=lane (within jblk), k=t (k>=8 -> 0)
    int id = gid - 2048;  // lane*32 + jblk*8 + t
    int lane = id >> 5, idx = id & 31;
    int jblk = idx >> 3, t = idx & 7;
    float v = (lane < 16) ? W1[(96 + t) * HF + jblk * 16 + lane] : 0.f;
    w1epk[id] = (_Float16)v;
  }
  // hist (deg zeroed by hipMemsetAsync before this kernel)
  atomicAdd(&deg[ei[NE + gid]], 1);
}

// ---- fill: packed 24B sorted records {int r, int c, half ea[8]} ----
__global__ __launch_bounds__(256) void fill_kernel(
    const int* __restrict__ ei, const float* __restrict__ ea,
    int* __restrict__ cur, char* __restrict__ recs) {
  int e = blockIdx.x * 256 + threadIdx.x;
  int r = ei[e];
  int c = ei[NE + e];
  int pos = atomicAdd(&cur[c], 1);
  const float4* p = (const float4*)(ea + (size_t)e * EFT);
  float4 v0 = p[0], v1 = p[1];
  union { _Float16 h[2]; int i; } p01, p23, p45, p67;
  p01.h[0] = (_Float16)v0.x; p01.h[1] = (_Float16)v0.y;
  p23.h[0] = (_Float16)v0.z; p23.h[1] = (_Float16)v0.w;
  p45.h[0] = (_Float16)v1.x; p45.h[1] = (_Float16)v1.y;
  p67.h[0] = (_Float16)v1.z; p67.h[1] = (_Float16)v1.w;
  int2* rp = (int2*)(recs + (size_t)pos * 24);
  int2 a = {r, c};
  int2 b = {p01.i, p23.i};
  int2 d = {p45.i, p67.i};
  rp[0] = a; rp[1] = b; rp[2] = d;
}

// ---- shared pre-body: MFMA ABh for 64 nodes of this block, outb rows in obs ----
__device__ inline void pre_body(int tid, int bbase64,
                                const float* __restrict__ x_s,
                                const _Float16 (*wlds)[72],
                                const _Float16 (*obs)[32],
                                _Float16* __restrict__ ABh) {
  int lcol = tid & 15, kgrp = (tid >> 4) & 3, wid = tid >> 6;
  int nodebase = bbase64 + wid * 16;
  int nodeA = nodebase + lcol;
  int ln = wid * 16 + lcol;

  half8 a0 = {}, a1 = {};
  if (nodeA < NN) {
    if (kgrp < 2) {
      const float4* p = (const float4*)(x_s + (size_t)nodeA * SF);
      float4 v0 = p[kgrp * 2], v1 = p[kgrp * 2 + 1];
      a0[0]=(_Float16)v0.x; a0[1]=(_Float16)v0.y;
      a0[2]=(_Float16)v0.z; a0[3]=(_Float16)v0.w;
      a0[4]=(_Float16)v1.x; a0[5]=(_Float16)v1.y;
      a0[6]=(_Float16)v1.z; a0[7]=(_Float16)v1.w;
      a1 = *(const half8*)(&obs[ln][16 + kgrp * 8]);
    } else if (kgrp == 2) {
      a0 = *(const half8*)(&obs[ln][0]);
    } else {
      a0 = *(const half8*)(&obs[ln][8]);
    }
  }

  floatx4 acc[8];
#pragma unroll
  for (int nt = 0; nt < 8; ++nt) {
    half8 b0 = *(const half8*)(&wlds[nt * 16 + lcol][kgrp * 8]);
    half8 b1v = *(const half8*)(&wlds[nt * 16 + lcol][32 + kgrp * 8]);
    floatx4 c = {0.f, 0.f, 0.f, 0.f};
    c = __builtin_amdgcn_mfma_f32_16x16x32_f16(a0, b0, c, 0, 0, 0);
    c = __builtin_amdgcn_mfma_f32_16x16x32_f16(a1, b1v, c, 0, 0, 0);
    acc[nt] = c;
  }

#pragma unroll
  for (int rr = 0; rr < 4; ++rr) {
    int node = nodebase + kgrp * 4 + rr;
    if (node < NN) {
      _Float16* dst = ABh + (size_t)node * 128;
#pragma unroll
      for (int nt = 0; nt < 8; ++nt)
        dst[nt * 16 + lcol] = (_Float16)acc[nt][rr];
    }
  }
}

// ---- initpre (grid 1563): out = x_t @ F0; outb/sums; then pre MFMA ----
__global__ __launch_bounds__(256) void initpre_kernel(
    const float* __restrict__ x_t, const float* __restrict__ F0,
    const float* __restrict__ x_s, const _Float16* __restrict__ WpreT,
    float* __restrict__ out, _Float16* __restrict__ outb,
    float* __restrict__ sums, _Float16* __restrict__ ABh) {
  __shared__ _Float16 wlds[128][72];
  __shared__ _Float16 obs[64][32];
  int tid = threadIdx.x;
  for (int t = tid; t < 1024; t += 256) {
    int colr = t >> 3, kc = t & 7;
    *(half8*)(&wlds[colr][kc * 8]) = *(const half8*)(WpreT + colr * 64 + kc * 8);
  }

  int nl = tid >> 2, q = tid & 3;
  int node = blockIdx.x * 64 + nl;
  if (node < NN) {
    float o[8];
#pragma unroll
    for (int jj = 0; jj < 8; ++jj) o[jj] = 0.f;
    const float4* xt4 = (const float4*)(x_t + (size_t)node * DF);
#pragma unroll
    for (int it = 0; it < 8; ++it) {
      float4 xv = xt4[it];
#pragma unroll
      for (int k = 0; k < 4; ++k) {
        float xk = (k == 0) ? xv.x : (k == 1) ? xv.y : (k == 2) ? xv.z : xv.w;
        const float* frow = F0 + (it * 4 + k) * DF + q * 8;
        float4 f0 = *(const float4*)(frow);
        float4 f1 = *(const float4*)(frow + 4);
        o[0] = fmaf(xk, f0.x, o[0]); o[1] = fmaf(xk, f0.y, o[1]);
        o[2] = fmaf(xk, f0.z, o[2]); o[3] = fmaf(xk, f0.w, o[3]);
        o[4] = fmaf(xk, f1.x, o[4]); o[5] = fmaf(xk, f1.y, o[5]);
        o[6] = fmaf(xk, f1.z, o[6]); o[7] = fmaf(xk, f1.w, o[7]);
      }
    }
    float4* op = (float4*)(out + (size_t)node * DF + q * 8);
    float4 w0 = {o[0], o[1], o[2], o[3]};
    float4 w1 = {o[4], o[5], o[6], o[7]};
    op[0] = w0; op[1] = w1;
    half8 pk;
#pragma unroll
    for (int jj = 0; jj < 8; ++jj) pk[jj] = (_Float16)o[jj];
    *(half8*)(outb + (size_t)node * DF + q * 8) = pk;
    *(half8*)(&obs[nl][q * 8]) = pk;
    float s = o[0]+o[1]+o[2]+o[3]+o[4]+o[5]+o[6]+o[7];
    s += __shfl_xor(s, 1, 64);
    s += __shfl_xor(s, 2, 64);
    if (q == 0) sums[node] = s;
  }
  __syncthreads();
  pre_body(tid, blockIdx.x * 64, x_s, wlds, obs, ABh);
}

// ---- nodepre (grid 1563): out += scattered @ Fk; zero scattered; pre MFMA ----
__global__ __launch_bounds__(256) void nodepre_kernel(
    float* __restrict__ out, float* __restrict__ scattered,
    const float* __restrict__ Fk,
    const float* __restrict__ x_s, const _Float16* __restrict__ WpreT,
    _Float16* __restrict__ outb, float* __restrict__ sums,
    _Float16* __restrict__ ABh) {
  __shared__ _Float16 wlds[128][72];
  __shared__ _Float16 obs[64][32];
  int tid = threadIdx.x;
  for (int t = tid; t < 1024; t += 256) {
    int colr = t >> 3, kc = t & 7;
    *(half8*)(&wlds[colr][kc * 8]) = *(const half8*)(WpreT + colr * 64 + kc * 8);
  }

  int nl = tid >> 2, q = tid & 3;
  int node = blockIdx.x * 64 + nl;
  if (node < NN) {
    float o[8];
    {
      const float4* op4 = (const float4*)(out + (size_t)node * DF + q * 8);
      float4 b0 = op4[0], b1 = op4[1];
      o[0]=b0.x; o[1]=b0.y; o[2]=b0.z; o[3]=b0.w;
      o[4]=b1.x; o[5]=b1.y; o[6]=b1.z; o[7]=b1.w;
    }
    const float4* sc4 = (const float4*)(scattered + (size_t)node * DF);
#pragma unroll
    for (int it = 0; it < 8; ++it) {
      float4 sv = sc4[it];
#pragma unroll
      for (int k = 0; k < 4; ++k) {
        float sk = (k == 0) ? sv.x : (k == 1) ? sv.y : (k == 2) ? sv.z : sv.w;
        const float* frow = Fk + (it * 4 + k) * DF + q * 8;
        float4 f0 = *(const float4*)(frow);
        float4 f1 = *(const float4*)(frow + 4);
        o[0] = fmaf(sk, f0.x, o[0]); o[1] = fmaf(sk, f0.y, o[1]);
        o[2] = fmaf(sk, f0.z, o[2]); o[3] = fmaf(sk, f0.w, o[3]);
        o[4] = fmaf(sk, f1.x, o[4]); o[5] = fmaf(sk, f1.y, o[5]);
        o[6] = fmaf(sk, f1.z, o[6]); o[7] = fmaf(sk, f1.w, o[7]);
      }
    }
    float4* op = (float4*)(out + (size_t)node * DF + q * 8);
    float4 w0 = {o[0], o[1], o[2], o[3]};
    float4 w1 = {o[4], o[5], o[6], o[7]};
    op[0] = w0; op[1] = w1;
    half8 pk;
#pragma unroll
    for (int jj = 0; jj < 8; ++jj) pk[jj] = (_Float16)o[jj];
    *(half8*)(outb + (size_t)node * DF + q * 8) = pk;
    *(half8*)(&obs[nl][q * 8]) = pk;
    float s = o[0]+o[1]+o[2]+o[3]+o[4]+o[5]+o[6]+o[7];
    s += __shfl_xor(s, 1, 64);
    s += __shfl_xor(s, 2, 64);
    if (q == 0) sums[node] = s;
    // zero own quarter of scattered (loads above already consumed: the FMA
    // chain forces vmcnt wait before these stores issue)
    float4 z = {0.f, 0.f, 0.f, 0.f};
    float4* zp = (float4*)(scattered + (size_t)node * DF + q * 8);
    zp[0] = z; zp[1] = z;
  }
  __syncthreads();
  pre_body(tid, blockIdx.x * 64, x_s, wlds, obs, ABh);
}

// ---------------- edge MLP (f16 MFMA) + owner-centric epilogue ----------------
__global__ __launch_bounds__(256, 4) void edge_kernel(
    const _Float16* __restrict__ ABh, const _Float16* __restrict__ outb,
    const float* __restrict__ sums, const char* __restrict__ recs,
    const float* __restrict__ b1, const float* __restrict__ b2,
    const _Float16* __restrict__ w2pk, const _Float16* __restrict__ w1epk,
    float* __restrict__ scattered) {
  // h: [256][64] halves, 128B rows, XOR-swizzled granules (32768 B)
  // sh: [256] rows of 33 f32 (33792 B) -> union 33792 B
  __shared__ union { _Float16 h[256 * 64]; float sh[256 * 33]; } u;
  __shared__ int scol[256];
  __shared__ unsigned short l0[256], l1[256];
  __shared__ int wbase[4];
  __shared__ int cnt;

  int tid = threadIdx.x;
  int bbase = blockIdx.x * 256;
  int i = bbase + tid;  // NE % 256 == 0: always valid
  if (tid == 0) cnt = 0;
  int lcol = tid & 15, kgrp = (tid >> 4) & 3, wid = tid >> 6;
  int lane = tid & 63;

  // load packed record {r, c, ea[8] f16}
  const int2* rp = (const int2*)(recs + (size_t)i * 24);
  int2 ra = rp[0], rb = rp[1], rd = rp[2];
  int r = ra.x;
  int c = ra.y;
  int4 eai = {rb.x, rb.y, rd.x, rd.y};
  scol[tid] = c;
  float s_r = sums[r], s_c = sums[c];

  // EARLY-ISSUE: stage A[r] and B[c] halves (128B each) into registers so
  // the HBM/L3 latency hides under phase-0's shuffles + MFMAs.
  half8 Ar[8], Bc[8];
  {
    const half8* arp = (const half8*)(ABh + (size_t)r * 128);
    const half8* bcp = (const half8*)(ABh + (size_t)c * 128 + 64);
#pragma unroll
    for (int q = 0; q < 8; ++q) { Ar[q] = arp[q]; Bc[q] = bcp[q]; }
  }

  float b2c0 = b2[lcol], b2c1 = b2[16 + lcol];

  // ---- phase 0: eaw^T = W1e^T @ ea via swapped MFMA -> swizzled half4 writes ----
  const _Float16* wep = w1epk + (size_t)lane * 32;
  half8 wA0 = *(const half8*)(wep);
  half8 wA1 = *(const half8*)(wep + 8);
  half8 wA2 = *(const half8*)(wep + 16);
  half8 wA3 = *(const half8*)(wep + 24);
  const float4* b1f4 = (const float4*)b1;
  float4 b1q0 = b1f4[0 + kgrp];
  float4 b1q1 = b1f4[4 + kgrp];
  float4 b1q2 = b1f4[8 + kgrp];
  float4 b1q3 = b1f4[12 + kgrp];
  bool lo16 = lane < 16;
#pragma unroll
  for (int g = 0; g < 4; ++g) {
    int src = g * 16 + lcol;
    int4 t;
    t.x = __shfl(eai.x, src, 64);
    t.y = __shfl(eai.y, src, 64);
    t.z = __shfl(eai.z, src, 64);
    t.w = __shfl(eai.w, src, 64);
    half8 zz = {};
    half8 bg = lo16 ? __builtin_bit_cast(half8, t) : zz;
    int erow = wid * 64 + g * 16 + lcol;
    {
      floatx4 cc = {b1q0.x, b1q0.y, b1q0.z, b1q0.w};
      cc = __builtin_amdgcn_mfma_f32_16x16x32_f16(wA0, bg, cc, 0, 0, 0);
      half4v h4 = {(_Float16)cc[0], (_Float16)cc[1], (_Float16)cc[2], (_Float16)cc[3]};
      *(half4v*)(&u.h[hswz(erow, 0 * 16 + kgrp * 4)]) = h4;
    }
    {
      floatx4 cc = {b1q1.x, b1q1.y, b1q1.z, b1q1.w};
      cc = __builtin_amdgcn_mfma_f32_16x16x32_f16(wA1, bg, cc, 0, 0, 0);
      half4v h4 = {(_Float16)cc[0], (_Float16)cc[1], (_Float16)cc[2], (_Float16)cc[3]};
      *(half4v*)(&u.h[hswz(erow, 1 * 16 + kgrp * 4)]) = h4;
    }
    {
      floatx4 cc = {b1q2.x, b1q2.y, b1q2.z, b1q2.w};
      cc = __builtin_amdgcn_mfma_f32_16x16x32_f16(wA2, bg, cc, 0, 0, 0);
      half4v h4 = {(_Float16)cc[0], (_Float16)cc[1], (_Float16)cc[2], (_Float16)cc[3]};
      *(half4v*)(&u.h[hswz(erow, 2 * 16 + kgrp * 4)]) = h4;
    }
    {
      floatx4 cc = {b1q3.x, b1q3.y, b1q3.z, b1q3.w};
      cc = __builtin_amdgcn_mfma_f32_16x16x32_f16(wA3, bg, cc, 0, 0, 0);
      half4v h4 = {(_Float16)cc[0], (_Float16)cc[1], (_Float16)cc[2], (_Float16)cc[3]};
      *(half4v*)(&u.h[hswz(erow, 3 * 16 + kgrp * 4)]) = h4;
    }
  }
  // phases 0-2 touch only this wave's h rows: wave-local, no block barrier

  // ---- phase 1: h = relu(A[r] + B[c] + eaw) packed f16, RMW on own row ----
#pragma unroll
  for (int q = 0; q < 8; ++q) {
    int idx = hswz(tid, q * 8);
    half8 w = *(const half8*)(&u.h[idx]);
    half8 s = Ar[q] + Bc[q] + w;
    short8 sb = __builtin_bit_cast(short8, s);
    short8 m = sb >> 15;
    sb = sb & ~m;  // relu: zero negatives (and -0)
    *(short8*)(&u.h[idx]) = sb;
  }

  // ---- phase 2: layer-2 MFMA, 4 groups of 16 edges per wave ----
  const _Float16* wpp = w2pk + (size_t)lane * 32;
  half8 w2f00 = *(const half8*)(wpp);
  half8 w2f01 = *(const half8*)(wpp + 8);
  half8 w2f10 = *(const half8*)(wpp + 16);
  half8 w2f11 = *(const half8*)(wpp + 24);
  floatx4 acc[4][2];
#pragma unroll
  for (int g = 0; g < 4; ++g) {
    int erow = wid * 64 + g * 16 + lcol;
    half8 a0 = *(const half8*)(&u.h[hswz(erow, kgrp * 8)]);
    half8 a1 = *(const half8*)(&u.h[hswz(erow, 32 + kgrp * 8)]);
    floatx4 c0 = {b2c0, b2c0, b2c0, b2c0};
    floatx4 c1 = {b2c1, b2c1, b2c1, b2c1};
    c0 = __builtin_amdgcn_mfma_f32_16x16x32_f16(a0, w2f00, c0, 0, 0, 0);
    c0 = __builtin_amdgcn_mfma_f32_16x16x32_f16(a1, w2f10, c0, 0, 0, 0);
    c1 = __builtin_amdgcn_mfma_f32_16x16x32_f16(a0, w2f01, c1, 0, 0, 0);
    c1 = __builtin_amdgcn_mfma_f32_16x16x32_f16(a1, w2f11, c1, 0, 0, 0);
    acc[g][0] = c0;
    acc[g][1] = c1;
  }

  // EARLY-ISSUE: outb rows for the epilogue, overlapping the barrier wait.
  half8 Or[4], Oc[4];
  {
    const half8* orp = (const half8*)(outb + (size_t)r * DF);
    const half8* ocp = (const half8*)(outb + (size_t)c * DF);
#pragma unroll
    for (int q = 0; q < 4; ++q) { Or[q] = orp[q]; Oc[q] = ocp[q]; }
  }

  // RACE FIX: all waves must finish phase-2 h reads before any sh writes
  // (the two union views have different row strides -> cross-wave overlap).
  __syncthreads();

  // ---- phase 3a: dump o (C-frags) to LDS, stride-33 f32 rows ----
#pragma unroll
  for (int g = 0; g < 4; ++g) {
#pragma unroll
    for (int rr = 0; rr < 4; ++rr) {
      int e = wid * 64 + g * 16 + kgrp * 4 + rr;
      u.sh[e * 33 + lcol]      = acc[g][0][rr];
      u.sh[e * 33 + 16 + lcol] = acc[g][1][rr];
    }
  }

  // ---- phase 3b: owner-centric norm + mask + shift (all wave-local) ----
  {
    float o2[32];
    float nsq = 0.f;
#pragma unroll
    for (int j = 0; j < 32; ++j) {
      float v = u.sh[tid * 33 + j];
      o2[j] = v;
      nsq = fmaf(v, v, nsq);
    }
    float ms = (nsq > 0.f) ? rsqrtf(nsq) : 0.f;
    if (s_r == 0.f && s_c == 0.f) ms = 0.f;
#pragma unroll
    for (int q = 0; q < 4; ++q) {
#pragma unroll
      for (int jj = 0; jj < 8; ++jj)
        u.sh[tid * 33 + q * 8 + jj] =
            ((float)Oc[q][jj] - (float)Or[q][jj]) * o2[q * 8 + jj] * ms;
    }
  }
  __syncthreads();  // cross-wave: sh rows + scol + cnt now visible

  // ---- phase 4: segmented reduce over sorted-col runs ----
  int c_self = scol[tid];
  bool head = (tid == 0 || scol[tid - 1] != c_self);
  unsigned long long m = __ballot(head);
  if (lane == 0) wbase[wid] = atomicAdd(&cnt, (int)__popcll(m));
  __syncthreads();
  if (head) {
    int idx = wbase[wid] + (int)__popcll(m & ((1ull << lane) - 1ull));
    int t1 = tid + 1;
    while (t1 < 256 && scol[t1] == c_self) ++t1;
    l0[idx] = (unsigned short)tid;
    l1[idx] = (unsigned short)t1;
  }
  __syncthreads();
  int nr = cnt;
  for (int task = tid; task < nr * 32; task += 256) {
    int rid = task >> 5, j = task & 31;
    int t0 = l0[rid], t1 = l1[rid];
    float s = 0.f;
    for (int t = t0; t < t1; ++t) s += u.sh[t * 33 + j];
    unsafeAtomicAdd(&scattered[(size_t)scol[t0] * DF + j], s);
  }
}

// --- final node update (k=1): out += scattered @ Fk (in place, trimmed) ---
__global__ __launch_bounds__(256) void node_final_kernel(
    float* __restrict__ out, const float* __restrict__ scattered,
    const float* __restrict__ Fk) {
  int n = blockIdx.x * 256 + threadIdx.x;
  if (n >= NN) return;
  float s[DF];
  const float4* sp = reinterpret_cast<const float4*>(scattered + (size_t)n * DF);
#pragma unroll
  for (int q = 0; q < 8; ++q) {
    float4 v = sp[q];
    s[4*q+0]=v.x; s[4*q+1]=v.y; s[4*q+2]=v.z; s[4*q+3]=v.w;
  }
  float4* op = reinterpret_cast<float4*>(out + (size_t)n * DF);
#pragma unroll
  for (int q = 0; q < 8; ++q) {
    float4 acc = op[q];
#pragma unroll
    for (int i = 0; i < DF; ++i) {
      float si = s[i];
      acc.x = fmaf(si, Fk[i*DF + 4*q+0], acc.x);
      acc.y = fmaf(si, Fk[i*DF + 4*q+1], acc.y);
      acc.z = fmaf(si, Fk[i*DF + 4*q+2], acc.z);
      acc.w = fmaf(si, Fk[i*DF + 4*q+3], acc.w);
    }
    op[q] = acc;
  }
}

extern "C" void kernel_launch(void* const* d_in, const int* in_sizes, int n_in,
                              void* d_out, int out_size, void* d_ws, size_t ws_size,
                              hipStream_t stream) {
  const float* x_s = (const float*)d_in[0];
  const float* x_t = (const float*)d_in[1];
  const int*   ei  = (const int*)d_in[2];
  const float* ea  = (const float*)d_in[3];
  const float* W1  = (const float*)d_in[4];
  const float* b1  = (const float*)d_in[5];
  const float* W2  = (const float*)d_in[6];
  const float* b2  = (const float*)d_in[7];
  const float* F   = (const float*)d_in[8];

  float* out = (float*)d_out;
  char* ws = (char*)d_ws;
  float*     scattered = (float*)(ws);                  // 12.8 MB
  _Float16*  ABh       = (_Float16*)(ws + 12800000);    // 25.6 MB
  _Float16*  outb      = (_Float16*)(ws + 38400000);    // 6.4 MB
  float*     sums      = (float*)(ws + 44800000);       // 0.4 MB
  char*      recs      = (char*)(ws + 45200000);        // 38.4 MB (24B/edge)
  int*       deg       = (int*)(ws + 83600000);         // 0.4 MB
  int*       cur       = (int*)(ws + 84000000);         // 0.4 MB
  int*       bsums     = (int*)(ws + 84400000);         // 4 KB
  _Float16*  WpreT     = (_Float16*)(ws + 84410000);    // 16 KB
  _Float16*  w2pk      = (_Float16*)(ws + 84430000);    // 4 KB
  _Float16*  w1epk     = (_Float16*)(ws + 84440000);    // 4 KB

  dim3 blk(256);
  dim3 grid_e(NE / 256);          // 6250, exact
  dim3 grid_n((NN + 255) / 256);  // 391
  dim3 grid_p((NN + 63) / 64);    // 1563
  int nscan = (NN + 1023) / 1024; // 98

  hipMemsetAsync(deg, 0, NN * sizeof(int), stream);
  setup_kernel<<<grid_e, blk, 0, stream>>>(ei, W1, W2, WpreT, w2pk, w1epk,
                                           (float4*)scattered, deg);
  scan1_kernel<<<nscan, blk, 0, stream>>>(deg, cur, bsums);
  scan3_kernel<<<grid_n, blk, 0, stream>>>(cur, bsums);
  fill_kernel<<<grid_e, blk, 0, stream>>>(ei, ea, cur, recs);

  initpre_kernel<<<grid_p, blk, 0, stream>>>(x_t, F, x_s, WpreT,
                                             out, outb, sums, ABh);
  edge_kernel<<<grid_e, blk, 0, stream>>>(ABh, outb, sums, recs, b1, b2,
                                          w2pk, w1epk, scattered);
  nodepre_kernel<<<grid_p, blk, 0, stream>>>(out, scattered,
                                             F + (size_t)1 * DF * DF,
                                             x_s, WpreT, outb, sums, ABh);
  edge_kernel<<<grid_e, blk, 0, stream>>>(ABh, outb, sums, recs, b1, b2,
                                          w2pk, w1epk, scattered);
  node_final_kernel<<<grid_n, blk, 0, stream>>>(out, scattered,
                                                F + (size_t)2 * DF * DF);
}

// Round 18
// 426.563 us; speedup vs baseline: 1.4142x; 1.0119x over previous
//
#include <hip/hip_runtime.h>

#define NN 100000
#define NE 1600000
#define SF 16
#define DF 32
#define EFT 8
#define HF 64

typedef __attribute__((ext_vector_type(8))) _Float16 half8;
typedef __attribute__((ext_vector_type(4))) _Float16 half4v;
typedef __attribute__((ext_vector_type(8))) short short8;
typedef __attribute__((ext_vector_type(4))) float floatx4;

// swizzled half-index into the [256][64] h tile (128B rows, 16B-granule XOR)
__device__ inline int hswz(int row, int halfoff) {
  int gran = halfoff >> 3, sub = halfoff & 7;
  return row * 64 + ((gran ^ (row & 7)) << 3) + sub;
}

// ---------------- CSR scan ----------------
__global__ __launch_bounds__(256) void scan1_kernel(const int* __restrict__ deg,
                                                    int* __restrict__ cur,
                                                    int* __restrict__ bsums) {
  __shared__ int ts[256];
  int tid = threadIdx.x;
  int base = blockIdx.x * 1024 + tid * 4;
  int v[4];
#pragma unroll
  for (int q = 0; q < 4; ++q) v[q] = (base + q < NN) ? deg[base + q] : 0;
  int s = v[0] + v[1] + v[2] + v[3];
  ts[tid] = s;
  __syncthreads();
  for (int off = 1; off < 256; off <<= 1) {
    int t = (tid >= off) ? ts[tid - off] : 0;
    __syncthreads();
    ts[tid] += t;
    __syncthreads();
  }
  int excl = ts[tid] - s;
  if (tid == 255) bsums[blockIdx.x] = ts[255];
  int run = excl;
#pragma unroll
  for (int q = 0; q < 4; ++q) {
    if (base + q < NN) cur[base + q] = run;
    run += v[q];
  }
}

__global__ __launch_bounds__(256) void scan3_kernel(int* __restrict__ cur,
                                                    const int* __restrict__ bsums) {
  int i = blockIdx.x * 256 + threadIdx.x;
  int g = blockIdx.x >> 2;
  int pref = 0;
  for (int q = 0; q < g; ++q) pref += bsums[q];
  if (i < NN) cur[i] += pref;
}

// ---- setup (grid 6250): zero scattered; pack tables; hist (deg pre-zeroed) ----
__global__ __launch_bounds__(256) void setup_kernel(
    const int* __restrict__ ei,
    const float* __restrict__ W1, const float* __restrict__ W2,
    _Float16* __restrict__ WpreT, _Float16* __restrict__ w2pk,
    _Float16* __restrict__ w1epk,
    float4* __restrict__ scattered4, int* __restrict__ deg) {
  int gid = blockIdx.x * 256 + threadIdx.x;
  if (gid < 800000) {
    float4 z = {0.f, 0.f, 0.f, 0.f};
    scattered4[gid] = z;
  }
  if (gid < 128 * 64) {
    int col = gid >> 6, k = gid & 63;
    int j = col & 63;
    bool bh = col >= 64;
    float v = 0.f;
    if (k < 16) v = W1[((bh ? 16 : 0) + k) * HF + j];
    else if (k < 48) v = W1[((bh ? 64 : 32) + (k - 16)) * HF + j];
    WpreT[gid] = (_Float16)v;
  }
  if (gid < 2048) {
    // W2 B-frags: lane holds col = nt*16+lcol, k = kt*32 + kgrp*8 + q
    int lane = gid >> 5, idx = gid & 31;
    int kt = idx >> 4, nt = (idx >> 3) & 1, q = idx & 7;
    int kgrp = (lane >> 4) & 3, lcol = lane & 15;
    w2pk[gid] = (_Float16)W2[(kt * 32 + kgrp * 8 + q) * DF + nt * 16 + lcol];
  } else if (gid < 4096) {
    // W1e^T A-frags: lane<16 holds row j=lane (within jblk), k=t (k>=8 -> 0)
    int id = gid - 2048;  // lane*32 + jblk*8 + t
    int lane = id >> 5, idx = id & 31;
    int jblk = idx >> 3, t = idx & 7;
    float v = (lane < 16) ? W1[(96 + t) * HF + jblk * 16 + lane] : 0.f;
    w1epk[id] = (_Float16)v;
  }
  // hist (deg zeroed by hipMemsetAsync before this kernel)
  atomicAdd(&deg[ei[NE + gid]], 1);
}

// ---- fill: packed 32B-aligned sorted records {int r, int c, half ea[8], pad} ----
__global__ __launch_bounds__(256) void fill_kernel(
    const int* __restrict__ ei, const float* __restrict__ ea,
    int* __restrict__ cur, char* __restrict__ recs) {
  int e = blockIdx.x * 256 + threadIdx.x;
  int r = ei[e];
  int c = ei[NE + e];
  int pos = atomicAdd(&cur[c], 1);
  const float4* p = (const float4*)(ea + (size_t)e * EFT);
  float4 v0 = p[0], v1 = p[1];
  union { _Float16 h[2]; int i; } p01, p23, p45, p67;
  p01.h[0] = (_Float16)v0.x; p01.h[1] = (_Float16)v0.y;
  p23.h[0] = (_Float16)v0.z; p23.h[1] = (_Float16)v0.w;
  p45.h[0] = (_Float16)v1.x; p45.h[1] = (_Float16)v1.y;
  p67.h[0] = (_Float16)v1.z; p67.h[1] = (_Float16)v1.w;
  int4* rp = (int4*)(recs + (size_t)pos * 32);
  int4 a = {r, c, p01.i, p23.i};
  int4 b = {p45.i, p67.i, 0, 0};
  rp[0] = a;
  rp[1] = b;
}

// ---- shared pre-body: MFMA ABh for 64 nodes of this block, outb rows in obs ----
__device__ inline void pre_body(int tid, int bbase64,
                                const float* __restrict__ x_s,
                                const _Float16 (*wlds)[72],
                                const _Float16 (*obs)[32],
                                _Float16* __restrict__ ABh) {
  int lcol = tid & 15, kgrp = (tid >> 4) & 3, wid = tid >> 6;
  int nodebase = bbase64 + wid * 16;
  int nodeA = nodebase + lcol;
  int ln = wid * 16 + lcol;

  half8 a0 = {}, a1 = {};
  if (nodeA < NN) {
    if (kgrp < 2) {
      const float4* p = (const float4*)(x_s + (size_t)nodeA * SF);
      float4 v0 = p[kgrp * 2], v1 = p[kgrp * 2 + 1];
      a0[0]=(_Float16)v0.x; a0[1]=(_Float16)v0.y;
      a0[2]=(_Float16)v0.z; a0[3]=(_Float16)v0.w;
      a0[4]=(_Float16)v1.x; a0[5]=(_Float16)v1.y;
      a0[6]=(_Float16)v1.z; a0[7]=(_Float16)v1.w;
      a1 = *(const half8*)(&obs[ln][16 + kgrp * 8]);
    } else if (kgrp == 2) {
      a0 = *(const half8*)(&obs[ln][0]);
    } else {
      a0 = *(const half8*)(&obs[ln][8]);
    }
  }

  floatx4 acc[8];
#pragma unroll
  for (int nt = 0; nt < 8; ++nt) {
    half8 b0 = *(const half8*)(&wlds[nt * 16 + lcol][kgrp * 8]);
    half8 b1v = *(const half8*)(&wlds[nt * 16 + lcol][32 + kgrp * 8]);
    floatx4 c = {0.f, 0.f, 0.f, 0.f};
    c = __builtin_amdgcn_mfma_f32_16x16x32_f16(a0, b0, c, 0, 0, 0);
    c = __builtin_amdgcn_mfma_f32_16x16x32_f16(a1, b1v, c, 0, 0, 0);
    acc[nt] = c;
  }

#pragma unroll
  for (int rr = 0; rr < 4; ++rr) {
    int node = nodebase + kgrp * 4 + rr;
    if (node < NN) {
      _Float16* dst = ABh + (size_t)node * 128;
#pragma unroll
      for (int nt = 0; nt < 8; ++nt)
        dst[nt * 16 + lcol] = (_Float16)acc[nt][rr];
    }
  }
}

// ---- initpre (grid 1563): out = x_t @ F0; outb/sums; then pre MFMA ----
__global__ __launch_bounds__(256) void initpre_kernel(
    const float* __restrict__ x_t, const float* __restrict__ F0,
    const float* __restrict__ x_s, const _Float16* __restrict__ WpreT,
    float* __restrict__ out, _Float16* __restrict__ outb,
    float* __restrict__ sums, _Float16* __restrict__ ABh) {
  __shared__ _Float16 wlds[128][72];
  __shared__ _Float16 obs[64][32];
  int tid = threadIdx.x;
  for (int t = tid; t < 1024; t += 256) {
    int colr = t >> 3, kc = t & 7;
    *(half8*)(&wlds[colr][kc * 8]) = *(const half8*)(WpreT + colr * 64 + kc * 8);
  }

  int nl = tid >> 2, q = tid & 3;
  int node = blockIdx.x * 64 + nl;
  if (node < NN) {
    float o[8];
#pragma unroll
    for (int jj = 0; jj < 8; ++jj) o[jj] = 0.f;
    const float4* xt4 = (const float4*)(x_t + (size_t)node * DF);
#pragma unroll
    for (int it = 0; it < 8; ++it) {
      float4 xv = xt4[it];
#pragma unroll
      for (int k = 0; k < 4; ++k) {
        float xk = (k == 0) ? xv.x : (k == 1) ? xv.y : (k == 2) ? xv.z : xv.w;
        const float* frow = F0 + (it * 4 + k) * DF + q * 8;
        float4 f0 = *(const float4*)(frow);
        float4 f1 = *(const float4*)(frow + 4);
        o[0] = fmaf(xk, f0.x, o[0]); o[1] = fmaf(xk, f0.y, o[1]);
        o[2] = fmaf(xk, f0.z, o[2]); o[3] = fmaf(xk, f0.w, o[3]);
        o[4] = fmaf(xk, f1.x, o[4]); o[5] = fmaf(xk, f1.y, o[5]);
        o[6] = fmaf(xk, f1.z, o[6]); o[7] = fmaf(xk, f1.w, o[7]);
      }
    }
    float4* op = (float4*)(out + (size_t)node * DF + q * 8);
    float4 w0 = {o[0], o[1], o[2], o[3]};
    float4 w1 = {o[4], o[5], o[6], o[7]};
    op[0] = w0; op[1] = w1;
    half8 pk;
#pragma unroll
    for (int jj = 0; jj < 8; ++jj) pk[jj] = (_Float16)o[jj];
    *(half8*)(outb + (size_t)node * DF + q * 8) = pk;
    *(half8*)(&obs[nl][q * 8]) = pk;
    float s = o[0]+o[1]+o[2]+o[3]+o[4]+o[5]+o[6]+o[7];
    s += __shfl_xor(s, 1, 64);
    s += __shfl_xor(s, 2, 64);
    if (q == 0) sums[node] = s;
  }
  __syncthreads();
  pre_body(tid, blockIdx.x * 64, x_s, wlds, obs, ABh);
}

// ---- nodepre (grid 1563): out += scattered @ Fk; zero scattered; pre MFMA ----
__global__ __launch_bounds__(256) void nodepre_kernel(
    float* __restrict__ out, float* __restrict__ scattered,
    const float* __restrict__ Fk,
    const float* __restrict__ x_s, const _Float16* __restrict__ WpreT,
    _Float16* __restrict__ outb, float* __restrict__ sums,
    _Float16* __restrict__ ABh) {
  __shared__ _Float16 wlds[128][72];
  __shared__ _Float16 obs[64][32];
  int tid = threadIdx.x;
  for (int t = tid; t < 1024; t += 256) {
    int colr = t >> 3, kc = t & 7;
    *(half8*)(&wlds[colr][kc * 8]) = *(const half8*)(WpreT + colr * 64 + kc * 8);
  }

  int nl = tid >> 2, q = tid & 3;
  int node = blockIdx.x * 64 + nl;
  if (node < NN) {
    float o[8];
    {
      const float4* op4 = (const float4*)(out + (size_t)node * DF + q * 8);
      float4 b0 = op4[0], b1 = op4[1];
      o[0]=b0.x; o[1]=b0.y; o[2]=b0.z; o[3]=b0.w;
      o[4]=b1.x; o[5]=b1.y; o[6]=b1.z; o[7]=b1.w;
    }
    const float4* sc4 = (const float4*)(scattered + (size_t)node * DF);
#pragma unroll
    for (int it = 0; it < 8; ++it) {
      float4 sv = sc4[it];
#pragma unroll
      for (int k = 0; k < 4; ++k) {
        float sk = (k == 0) ? sv.x : (k == 1) ? sv.y : (k == 2) ? sv.z : sv.w;
        const float* frow = Fk + (it * 4 + k) * DF + q * 8;
        float4 f0 = *(const float4*)(frow);
        float4 f1 = *(const float4*)(frow + 4);
        o[0] = fmaf(sk, f0.x, o[0]); o[1] = fmaf(sk, f0.y, o[1]);
        o[2] = fmaf(sk, f0.z, o[2]); o[3] = fmaf(sk, f0.w, o[3]);
        o[4] = fmaf(sk, f1.x, o[4]); o[5] = fmaf(sk, f1.y, o[5]);
        o[6] = fmaf(sk, f1.z, o[6]); o[7] = fmaf(sk, f1.w, o[7]);
      }
    }
    float4* op = (float4*)(out + (size_t)node * DF + q * 8);
    float4 w0 = {o[0], o[1], o[2], o[3]};
    float4 w1 = {o[4], o[5], o[6], o[7]};
    op[0] = w0; op[1] = w1;
    half8 pk;
#pragma unroll
    for (int jj = 0; jj < 8; ++jj) pk[jj] = (_Float16)o[jj];
    *(half8*)(outb + (size_t)node * DF + q * 8) = pk;
    *(half8*)(&obs[nl][q * 8]) = pk;
    float s = o[0]+o[1]+o[2]+o[3]+o[4]+o[5]+o[6]+o[7];
    s += __shfl_xor(s, 1, 64);
    s += __shfl_xor(s, 2, 64);
    if (q == 0) sums[node] = s;
    // zero own quarter of scattered (loads above already consumed: the FMA
    // chain forces vmcnt wait before these stores issue)
    float4 z = {0.f, 0.f, 0.f, 0.f};
    float4* zp = (float4*)(scattered + (size_t)node * DF + q * 8);
    zp[0] = z; zp[1] = z;
  }
  __syncthreads();
  pre_body(tid, blockIdx.x * 64, x_s, wlds, obs, ABh);
}

// ---------------- edge MLP (f16 MFMA) + owner-centric epilogue ----------------
__global__ __launch_bounds__(256, 4) void edge_kernel(
    const _Float16* __restrict__ ABh, const _Float16* __restrict__ outb,
    const float* __restrict__ sums, const char* __restrict__ recs,
    const float* __restrict__ b1, const float* __restrict__ b2,
    const _Float16* __restrict__ w2pk, const _Float16* __restrict__ w1epk,
    float* __restrict__ scattered) {
  // h: [256][64] halves, 128B rows, XOR-swizzled granules (32768 B)
  // sh: [256] rows of 33 f32 (33792 B) -> union 33792 B
  __shared__ union { _Float16 h[256 * 64]; float sh[256 * 33]; } u;
  __shared__ int scol[256];
  __shared__ unsigned short l0[256], l1[256];
  __shared__ int wbase[4];
  __shared__ int cnt;

  int tid = threadIdx.x;
  int bbase = blockIdx.x * 256;
  int i = bbase + tid;  // NE % 256 == 0: always valid
  if (tid == 0) cnt = 0;
  int lcol = tid & 15, kgrp = (tid >> 4) & 3, wid = tid >> 6;
  int lane = tid & 63;

  // load packed 32B record {r, c, ea[8] f16, pad}
  const int4* rp = (const int4*)(recs + (size_t)i * 32);
  int4 ra = rp[0];
  int4 rb = rp[1];
  int r = ra.x;
  int c = ra.y;
  int4 eai = {ra.z, ra.w, rb.x, rb.y};
  scol[tid] = c;
  float s_r = sums[r], s_c = sums[c];

  // EARLY-ISSUE: stage A[r] and B[c] halves (128B each) into registers so
  // the HBM/L3 latency hides under phase-0's shuffles + MFMAs.
  half8 Ar[8], Bc[8];
  {
    const half8* arp = (const half8*)(ABh + (size_t)r * 128);
    const half8* bcp = (const half8*)(ABh + (size_t)c * 128 + 64);
#pragma unroll
    for (int q = 0; q < 8; ++q) { Ar[q] = arp[q]; Bc[q] = bcp[q]; }
  }

  float b2c0 = b2[lcol], b2c1 = b2[16 + lcol];

  // ---- phase 0: eaw^T = W1e^T @ ea via swapped MFMA -> swizzled half4 writes ----
  const _Float16* wep = w1epk + (size_t)lane * 32;
  half8 wA0 = *(const half8*)(wep);
  half8 wA1 = *(const half8*)(wep + 8);
  half8 wA2 = *(const half8*)(wep + 16);
  half8 wA3 = *(const half8*)(wep + 24);
  const float4* b1f4 = (const float4*)b1;
  float4 b1q0 = b1f4[0 + kgrp];
  float4 b1q1 = b1f4[4 + kgrp];
  float4 b1q2 = b1f4[8 + kgrp];
  float4 b1q3 = b1f4[12 + kgrp];
  bool lo16 = lane < 16;
#pragma unroll
  for (int g = 0; g < 4; ++g) {
    int src = g * 16 + lcol;
    int4 t;
    t.x = __shfl(eai.x, src, 64);
    t.y = __shfl(eai.y, src, 64);
    t.z = __shfl(eai.z, src, 64);
    t.w = __shfl(eai.w, src, 64);
    half8 zz = {};
    half8 bg = lo16 ? __builtin_bit_cast(half8, t) : zz;
    int erow = wid * 64 + g * 16 + lcol;
    {
      floatx4 cc = {b1q0.x, b1q0.y, b1q0.z, b1q0.w};
      cc = __builtin_amdgcn_mfma_f32_16x16x32_f16(wA0, bg, cc, 0, 0, 0);
      half4v h4 = {(_Float16)cc[0], (_Float16)cc[1], (_Float16)cc[2], (_Float16)cc[3]};
      *(half4v*)(&u.h[hswz(erow, 0 * 16 + kgrp * 4)]) = h4;
    }
    {
      floatx4 cc = {b1q1.x, b1q1.y, b1q1.z, b1q1.w};
      cc = __builtin_amdgcn_mfma_f32_16x16x32_f16(wA1, bg, cc, 0, 0, 0);
      half4v h4 = {(_Float16)cc[0], (_Float16)cc[1], (_Float16)cc[2], (_Float16)cc[3]};
      *(half4v*)(&u.h[hswz(erow, 1 * 16 + kgrp * 4)]) = h4;
    }
    {
      floatx4 cc = {b1q2.x, b1q2.y, b1q2.z, b1q2.w};
      cc = __builtin_amdgcn_mfma_f32_16x16x32_f16(wA2, bg, cc, 0, 0, 0);
      half4v h4 = {(_Float16)cc[0], (_Float16)cc[1], (_Float16)cc[2], (_Float16)cc[3]};
      *(half4v*)(&u.h[hswz(erow, 2 * 16 + kgrp * 4)]) = h4;
    }
    {
      floatx4 cc = {b1q3.x, b1q3.y, b1q3.z, b1q3.w};
      cc = __builtin_amdgcn_mfma_f32_16x16x32_f16(wA3, bg, cc, 0, 0, 0);
      half4v h4 = {(_Float16)cc[0], (_Float16)cc[1], (_Float16)cc[2], (_Float16)cc[3]};
      *(half4v*)(&u.h[hswz(erow, 3 * 16 + kgrp * 4)]) = h4;
    }
  }
  // phases 0-2 touch only this wave's h rows: wave-local, no block barrier

  // ---- phase 1: h = relu(A[r] + B[c] + eaw) packed f16, RMW on own row ----
#pragma unroll
  for (int q = 0; q < 8; ++q) {
    int idx = hswz(tid, q * 8);
    half8 w = *(const half8*)(&u.h[idx]);
    half8 s = Ar[q] + Bc[q] + w;
    short8 sb = __builtin_bit_cast(short8, s);
    short8 m = sb >> 15;
    sb = sb & ~m;  // relu: zero negatives (and -0)
    *(short8*)(&u.h[idx]) = sb;
  }

  // ---- phase 2: layer-2 MFMA, 4 groups of 16 edges per wave ----
  const _Float16* wpp = w2pk + (size_t)lane * 32;
  half8 w2f00 = *(const half8*)(wpp);
  half8 w2f01 = *(const half8*)(wpp + 8);
  half8 w2f10 = *(const half8*)(wpp + 16);
  half8 w2f11 = *(const half8*)(wpp + 24);
  floatx4 acc[4][2];
#pragma unroll
  for (int g = 0; g < 4; ++g) {
    int erow = wid * 64 + g * 16 + lcol;
    half8 a0 = *(const half8*)(&u.h[hswz(erow, kgrp * 8)]);
    half8 a1 = *(const half8*)(&u.h[hswz(erow, 32 + kgrp * 8)]);
    floatx4 c0 = {b2c0, b2c0, b2c0, b2c0};
    floatx4 c1 = {b2c1, b2c1, b2c1, b2c1};
    c0 = __builtin_amdgcn_mfma_f32_16x16x32_f16(a0, w2f00, c0, 0, 0, 0);
    c0 = __builtin_amdgcn_mfma_f32_16x16x32_f16(a1, w2f10, c0, 0, 0, 0);
    c1 = __builtin_amdgcn_mfma_f32_16x16x32_f16(a0, w2f01, c1, 0, 0, 0);
    c1 = __builtin_amdgcn_mfma_f32_16x16x32_f16(a1, w2f11, c1, 0, 0, 0);
    acc[g][0] = c0;
    acc[g][1] = c1;
  }

  // EARLY-ISSUE: outb rows for the epilogue, overlapping the barrier wait.
  half8 Or[4], Oc[4];
  {
    const half8* orp = (const half8*)(outb + (size_t)r * DF);
    const half8* ocp = (const half8*)(outb + (size_t)c * DF);
#pragma unroll
    for (int q = 0; q < 4; ++q) { Or[q] = orp[q]; Oc[q] = ocp[q]; }
  }

  // RACE FIX: all waves must finish phase-2 h reads before any sh writes
  // (the two union views have different row strides -> cross-wave overlap).
  __syncthreads();

  // ---- phase 3a: dump o (C-frags) to LDS, stride-33 f32 rows ----
#pragma unroll
  for (int g = 0; g < 4; ++g) {
#pragma unroll
    for (int rr = 0; rr < 4; ++rr) {
      int e = wid * 64 + g * 16 + kgrp * 4 + rr;
      u.sh[e * 33 + lcol]      = acc[g][0][rr];
      u.sh[e * 33 + 16 + lcol] = acc[g][1][rr];
    }
  }

  // ---- phase 3b: owner-centric norm + mask + shift (all wave-local) ----
  {
    float o2[32];
    float nsq = 0.f;
#pragma unroll
    for (int j = 0; j < 32; ++j) {
      float v = u.sh[tid * 33 + j];
      o2[j] = v;
      nsq = fmaf(v, v, nsq);
    }
    float ms = (nsq > 0.f) ? rsqrtf(nsq) : 0.f;
    if (s_r == 0.f && s_c == 0.f) ms = 0.f;
#pragma unroll
    for (int q = 0; q < 4; ++q) {
#pragma unroll
      for (int jj = 0; jj < 8; ++jj)
        u.sh[tid * 33 + q * 8 + jj] =
            ((float)Oc[q][jj] - (float)Or[q][jj]) * o2[q * 8 + jj] * ms;
    }
  }
  __syncthreads();  // cross-wave: sh rows + scol + cnt now visible

  // ---- phase 4: segmented reduce over sorted-col runs ----
  int c_self = scol[tid];
  bool head = (tid == 0 || scol[tid - 1] != c_self);
  unsigned long long m = __ballot(head);
  if (lane == 0) wbase[wid] = atomicAdd(&cnt, (int)__popcll(m));
  __syncthreads();
  if (head) {
    int idx = wbase[wid] + (int)__popcll(m & ((1ull << lane) - 1ull));
    int t1 = tid + 1;
    while (t1 < 256 && scol[t1] == c_self) ++t1;
    l0[idx] = (unsigned short)tid;
    l1[idx] = (unsigned short)t1;
  }
  __syncthreads();
  int nr = cnt;
  for (int task = tid; task < nr * 32; task += 256) {
    int rid = task >> 5, j = task & 31;
    int t0 = l0[rid], t1 = l1[rid];
    float s = 0.f;
    for (int t = t0; t < t1; ++t) s += u.sh[t * 33 + j];
    unsafeAtomicAdd(&scattered[(size_t)scol[t0] * DF + j], s);
  }
}

// --- final node update (k=1): out += scattered @ Fk (in place, trimmed) ---
__global__ __launch_bounds__(256) void node_final_kernel(
    float* __restrict__ out, const float* __restrict__ scattered,
    const float* __restrict__ Fk) {
  int n = blockIdx.x * 256 + threadIdx.x;
  if (n >= NN) return;
  float s[DF];
  const float4* sp = reinterpret_cast<const float4*>(scattered + (size_t)n * DF);
#pragma unroll
  for (int q = 0; q < 8; ++q) {
    float4 v = sp[q];
    s[4*q+0]=v.x; s[4*q+1]=v.y; s[4*q+2]=v.z; s[4*q+3]=v.w;
  }
  float4* op = reinterpret_cast<float4*>(out + (size_t)n * DF);
#pragma unroll
  for (int q = 0; q < 8; ++q) {
    float4 acc = op[q];
#pragma unroll
    for (int i = 0; i < DF; ++i) {
      float si = s[i];
      acc.x = fmaf(si, Fk[i*DF + 4*q+0], acc.x);
      acc.y = fmaf(si, Fk[i*DF + 4*q+1], acc.y);
      acc.z = fmaf(si, Fk[i*DF + 4*q+2], acc.z);
      acc.w = fmaf(si, Fk[i*DF + 4*q+3], acc.w);
    }
    op[q] = acc;
  }
}

extern "C" void kernel_launch(void* const* d_in, const int* in_sizes, int n_in,
                              void* d_out, int out_size, void* d_ws, size_t ws_size,
                              hipStream_t stream) {
  const float* x_s = (const float*)d_in[0];
  const float* x_t = (const float*)d_in[1];
  const int*   ei  = (const int*)d_in[2];
  const float* ea  = (const float*)d_in[3];
  const float* W1  = (const float*)d_in[4];
  const float* b1  = (const float*)d_in[5];
  const float* W2  = (const float*)d_in[6];
  const float* b2  = (const float*)d_in[7];
  const float* F   = (const float*)d_in[8];

  float* out = (float*)d_out;
  char* ws = (char*)d_ws;
  float*     scattered = (float*)(ws);                  // 12.8 MB
  _Float16*  ABh       = (_Float16*)(ws + 12800000);    // 25.6 MB
  _Float16*  outb      = (_Float16*)(ws + 38400000);    // 6.4 MB
  float*     sums      = (float*)(ws + 44800000);       // 0.4 MB
  char*      recs      = (char*)(ws + 45200000);        // 51.2 MB (32B/edge)
  int*       deg       = (int*)(ws + 96400000);         // 0.4 MB
  int*       cur       = (int*)(ws + 96800000);         // 0.4 MB
  int*       bsums     = (int*)(ws + 97200000);         // 4 KB
  _Float16*  WpreT     = (_Float16*)(ws + 97210000);    // 16 KB
  _Float16*  w2pk      = (_Float16*)(ws + 97230000);    // 4 KB
  _Float16*  w1epk     = (_Float16*)(ws + 97240000);    // 4 KB
  // ws usage ~97.3 MB; round-6's fill<true> profile proved ws_size >= 263 MB.

  dim3 blk(256);
  dim3 grid_e(NE / 256);          // 6250, exact
  dim3 grid_n((NN + 255) / 256);  // 391
  dim3 grid_p((NN + 63) / 64);    // 1563
  int nscan = (NN + 1023) / 1024; // 98

  hipMemsetAsync(deg, 0, NN * sizeof(int), stream);
  setup_kernel<<<grid_e, blk, 0, stream>>>(ei, W1, W2, WpreT, w2pk, w1epk,
                                           (float4*)scattered, deg);
  scan1_kernel<<<nscan, blk, 0, stream>>>(deg, cur, bsums);
  scan3_kernel<<<grid_n, blk, 0, stream>>>(cur, bsums);
  fill_kernel<<<grid_e, blk, 0, stream>>>(ei, ea, cur, recs);

  initpre_kernel<<<grid_p, blk, 0, stream>>>(x_t, F, x_s, WpreT,
                                             out, outb, sums, ABh);
  edge_kernel<<<grid_e, blk, 0, stream>>>(ABh, outb, sums, recs, b1, b2,
                                          w2pk, w1epk, scattered);
  nodepre_kernel<<<grid_p, blk, 0, stream>>>(out, scattered,
                                             F + (size_t)1 * DF * DF,
                                             x_s, WpreT, outb, sums, ABh);
  edge_kernel<<<grid_e, blk, 0, stream>>>(ABh, outb, sums, recs, b1, b2,
                                          w2pk, w1epk, scattered);
  node_final_kernel<<<grid_n, blk, 0, stream>>>(out, scattered,
                                                F + (size_t)2 * DF * DF);
}